// Round 1
// baseline (16177.589 us; speedup 1.0000x reference)
//
#include <hip/hip_runtime.h>
#include <cmath>

constexpr int kN = 1024;
constexpr int kB = 64;
constexpr int kT = 12;
constexpr int kH = 64;
constexpr int kE = 16;
constexpr long long OUT0 = (long long)kB * kT * kN * kH;  // 50331648

struct StepPtrs {
  const float* s0;
  const float* s1;
  const float* zr;
  const float* x;
  const float* ax;
  const float* d1;
  const float* d2;
  const float* d3;
};

__device__ __forceinline__ float sig_(float v) { return 1.f / (1.f + expf(-v)); }

// ---------------- A = softmax(relu(E E^T), axis=1); also A^T ----------------
__global__ void __launch_bounds__(256) compute_A(const float* __restrict__ E,
                                                 float* __restrict__ A,
                                                 float* __restrict__ AT) {
  int n = blockIdx.x, tx = threadIdx.x;
  __shared__ float En[kE];
  __shared__ float red[4];
  if (tx < kE) En[tx] = E[n * kE + tx];
  __syncthreads();
  float v[4];
  float mx = 0.f;  // relu >= 0 so max >= 0
#pragma unroll
  for (int i = 0; i < 4; ++i) {
    int m = tx + i * 256;
    float s = 0.f;
#pragma unroll
    for (int d = 0; d < kE; ++d) s += En[d] * E[m * kE + d];
    s = fmaxf(s, 0.f);
    v[i] = s;
    mx = fmaxf(mx, s);
  }
#pragma unroll
  for (int off = 32; off; off >>= 1) mx = fmaxf(mx, __shfl_down(mx, off));
  int wid = tx >> 6, lane = tx & 63;
  if (lane == 0) red[wid] = mx;
  __syncthreads();
  mx = fmaxf(fmaxf(red[0], red[1]), fmaxf(red[2], red[3]));
  __syncthreads();
  float sum = 0.f;
#pragma unroll
  for (int i = 0; i < 4; ++i) {
    v[i] = expf(v[i] - mx);
    sum += v[i];
  }
#pragma unroll
  for (int off = 32; off; off >>= 1) sum += __shfl_down(sum, off);
  if (lane == 0) red[wid] = sum;
  __syncthreads();
  sum = red[0] + red[1] + red[2] + red[3];
  float inv = 1.f / sum;
#pragma unroll
  for (int i = 0; i < 4; ++i) {
    int m = tx + i * 256;
    float a = v[i] * inv;
    A[n * kN + m] = a;
    AT[m * kN + n] = a;
  }
}

// ---------------- per-node weights: out[n][ki][o] = sum_d E[n,d] W[d,k,i,o] --
// layer0 ki order is permuted: per k, [state(64) -> i=c+2, x(2) -> i=c-64]
__global__ void __launch_bounds__(256) mkw(const float* __restrict__ E,
                                           const float* __restrict__ Wsrc,
                                           float* __restrict__ out,
                                           int KI, int O, int Kdim, int Idim, int permuteL0) {
  int kio = blockIdx.x * 256 + threadIdx.x;
  int total = KI * O;
  int n0 = blockIdx.y * 128;
  __shared__ float Es[128][kE + 1];
  for (int idx = threadIdx.x; idx < 128 * kE; idx += 256)
    Es[idx >> 4][idx & 15] = E[(n0 + (idx >> 4)) * kE + (idx & 15)];
  __syncthreads();
  if (kio >= total) return;
  int ki = kio / O, o = kio - ki * O;
  int kper = KI / Kdim;
  int k = ki / kper, c = ki - k * kper;
  int i = permuteL0 ? (c < kH ? c + 2 : c - kH) : c;
  float w[kE];
#pragma unroll
  for (int d = 0; d < kE; ++d) w[d] = Wsrc[((d * Kdim + k) * Idim + i) * O + o];
  for (int nn = 0; nn < 128; ++nn) {
    float acc = 0.f;
#pragma unroll
    for (int d = 0; d < kE; ++d) acc += Es[nn][d] * w[d];
    out[(((long long)(n0 + nn)) * KI + ki) * O + o] = acc;
  }
}

// ---------------- Ax[b,t,n,c] = sum_m A[n,m] x[b,t,m,c], c<2 (one-time) -----
__global__ void __launch_bounds__(256) diffuse_x(const float* __restrict__ AT,
                                                 const float* __restrict__ x,
                                                 float* __restrict__ Ax) {
  int bt = blockIdx.x;  // b*T + t
  int tx = threadIdx.x;
  float acc[4][2] = {};
  for (int m = 0; m < kN; ++m) {
    float2 xv = *(const float2*)&x[((long long)bt * kN + m) * 2];
#pragma unroll
    for (int i = 0; i < 4; ++i) {
      float a = AT[m * kN + tx + i * 256];
      acc[i][0] += a * xv.x;
      acc[i][1] += a * xv.y;
    }
  }
#pragma unroll
  for (int i = 0; i < 4; ++i) {
    int n = tx + i * 256;
    Ax[((long long)bt * kN + n) * 2 + 0] = acc[i][0];
    Ax[((long long)bt * kN + n) * 2 + 1] = acc[i][1];
  }
}

// ---------------- out[b,n,c<64] = sum_m A[n,m] * p1[b,m,c] (*mul[b,m,c]) ----
// block tile 128n x 64c, thread tile 8n x 4c
__global__ void __launch_bounds__(256) diffuse64(const float* __restrict__ A,
                                                 const float* __restrict__ p1,
                                                 const float* __restrict__ mul,
                                                 float* __restrict__ out) {
  int b = blockIdx.y;
  int n0 = blockIdx.x * 128;
  int tx = threadIdx.x;
  int tn = tx >> 4;  // 0..15 -> 8 n each
  int tc = tx & 15;  // 0..15 -> 4 c each
  __shared__ float At[32][132];  // [m][n]
  __shared__ float Vs[32][68];   // [m][c]
  float acc[8][4] = {};
  for (int mt = 0; mt < 32; ++mt) {
    int m0 = mt * 32;
    for (int idx = tx; idx < 4096; idx += 256) {
      int i = idx >> 5, j = idx & 31;
      At[j][i] = A[(n0 + i) * kN + m0 + j];
    }
    if (mul) {
      for (int idx = tx; idx < 2048; idx += 256) {
        int mm = idx >> 6, c = idx & 63;
        long long row = (long long)b * kN + m0 + mm;
        Vs[mm][c] = p1[row * 64 + c] * mul[row * 128 + c];
      }
    } else {
      for (int idx = tx; idx < 2048; idx += 256) {
        int mm = idx >> 6, c = idx & 63;
        long long row = (long long)b * kN + m0 + mm;
        Vs[mm][c] = p1[row * 64 + c];
      }
    }
    __syncthreads();
#pragma unroll 8
    for (int mm = 0; mm < 32; ++mm) {
      float4 a0 = *(const float4*)&At[mm][tn * 8];
      float4 a1 = *(const float4*)&At[mm][tn * 8 + 4];
      float4 vv = *(const float4*)&Vs[mm][tc * 4];
      float a[8] = {a0.x, a0.y, a0.z, a0.w, a1.x, a1.y, a1.z, a1.w};
#pragma unroll
      for (int r = 0; r < 8; ++r) {
        acc[r][0] += a[r] * vv.x;
        acc[r][1] += a[r] * vv.y;
        acc[r][2] += a[r] * vv.z;
        acc[r][3] += a[r] * vv.w;
      }
    }
    __syncthreads();
  }
#pragma unroll
  for (int r = 0; r < 8; ++r) {
    int n = n0 + tn * 8 + r;
    float4 res = make_float4(acc[r][0], acc[r][1], acc[r][2], acc[r][3]);
    *(float4*)&out[((long long)b * kN + n) * 64 + tc * 4] = res;
  }
}

// ---------------- per-node GEMM + fused gate epilogue -----------------------
// VAR: 0=L0G 1=L0U 2=L1G 3=L1U. Block = one node n; out tile 64b x O.
template <int VAR>
__device__ __forceinline__ float xval(const StepPtrs& P, int b, int n, int ki, int t) {
  long long bn = (long long)b * kN + n;
  if (VAR == 0) {
    if (ki < 64) return P.s0[bn * 64 + ki];
    if (ki < 66) return P.x[(((long long)b * kT + t) * kN + n) * 2 + (ki - 64)];
    if (ki < 130) return P.d1[bn * 64 + (ki - 66)];
    return P.ax[(((long long)b * kT + t) * kN + n) * 2 + (ki - 130)];
  } else if (VAR == 1) {
    if (ki < 64) return P.s0[bn * 64 + ki] * P.zr[bn * 128 + ki];
    if (ki < 66) return P.x[(((long long)b * kT + t) * kN + n) * 2 + (ki - 64)];
    if (ki < 130) return P.d1[bn * 64 + (ki - 66)];
    return P.ax[(((long long)b * kT + t) * kN + n) * 2 + (ki - 130)];
  } else if (VAR == 2) {
    if (ki < 64) return P.s0[bn * 64 + ki];
    if (ki < 128) return P.s1[bn * 64 + (ki - 64)];
    if (ki < 192) return P.d2[bn * 64 + (ki - 128)];
    return P.d3[bn * 64 + (ki - 192)];
  } else {
    if (ki < 64) return P.s0[bn * 64 + ki];
    if (ki < 128) return P.s1[bn * 64 + (ki - 64)] * P.zr[bn * 128 + (ki - 64)];
    if (ki < 192) return P.d2[bn * 64 + (ki - 128)];
    return P.d3[bn * 64 + (ki - 192)];
  }
}

template <int VAR, int O, int KC>
__global__ void __launch_bounds__(256) gemm_node(StepPtrs P, const float* __restrict__ W,
                                                 const float* __restrict__ bias,
                                                 float* __restrict__ zr_out,
                                                 float* __restrict__ state_out,
                                                 float* __restrict__ seq_out,
                                                 float* __restrict__ last_out, int t) {
  constexpr int OG = O / 4;
  constexpr int BG = 256 / OG;
  constexpr int TB = 64 / BG;
  constexpr int NKT = (KC + 31) / 32;
  int n = blockIdx.x;
  int tx = threadIdx.x;
  int og = tx % OG, bg = tx / OG;
  int o0 = og * 4, b0 = bg * TB;
  __shared__ float Xs[32][68];
  __shared__ float Ws[32][O];
  float acc[TB][4] = {};
  for (int kt = 0; kt < NKT; ++kt) {
    int kbase = kt * 32;
    for (int idx = tx; idx < 2048; idx += 256) {
      int bb = idx >> 5, kk = idx & 31;
      int kig = kbase + kk;
      Xs[kk][bb] = (kig < KC) ? xval<VAR>(P, bb, n, kig, t) : 0.f;
    }
    for (int idx = tx; idx < 32 * O; idx += 256) {
      int kk = idx / O, oo = idx - kk * O;
      int kig = kbase + kk;
      Ws[kk][oo] = (kig < KC) ? W[((long long)n * KC + kig) * O + oo] : 0.f;
    }
    __syncthreads();
#pragma unroll 4
    for (int kk = 0; kk < 32; ++kk) {
      float4 wv = *(const float4*)&Ws[kk][o0];
      float xv[TB];
#pragma unroll
      for (int r = 0; r < TB; r += 4) {
        float4 xq = *(const float4*)&Xs[kk][b0 + r];
        xv[r] = xq.x; xv[r + 1] = xq.y; xv[r + 2] = xq.z; xv[r + 3] = xq.w;
      }
#pragma unroll
      for (int r = 0; r < TB; ++r) {
        acc[r][0] += xv[r] * wv.x;
        acc[r][1] += xv[r] * wv.y;
        acc[r][2] += xv[r] * wv.z;
        acc[r][3] += xv[r] * wv.w;
      }
    }
    __syncthreads();
  }
  if constexpr (O == 128) {  // gate gconv -> zr = sigmoid(.)
    float4 bb4 = *(const float4*)&bias[n * 128 + o0];
#pragma unroll
    for (int r = 0; r < TB; ++r) {
      long long bn = (long long)(b0 + r) * kN + n;
      float4 res;
      res.x = sig_(acc[r][0] + bb4.x);
      res.y = sig_(acc[r][1] + bb4.y);
      res.z = sig_(acc[r][2] + bb4.z);
      res.w = sig_(acc[r][3] + bb4.w);
      *(float4*)&zr_out[bn * 128 + o0] = res;
    }
  } else {  // update gconv -> h = r*s + (1-r)*tanh(.)
    const float* sptr = (VAR == 1) ? P.s0 : P.s1;
    float4 bb4 = *(const float4*)&bias[n * 64 + o0];
#pragma unroll
    for (int r = 0; r < TB; ++r) {
      int b = b0 + r;
      long long bn = (long long)b * kN + n;
      float4 rr = *(const float4*)&P.zr[bn * 128 + 64 + o0];
      float4 ss = *(const float4*)&sptr[bn * 64 + o0];
      float4 h;
      h.x = rr.x * ss.x + (1.f - rr.x) * tanhf(acc[r][0] + bb4.x);
      h.y = rr.y * ss.y + (1.f - rr.y) * tanhf(acc[r][1] + bb4.y);
      h.z = rr.z * ss.z + (1.f - rr.z) * tanhf(acc[r][2] + bb4.z);
      h.w = rr.w * ss.w + (1.f - rr.w) * tanhf(acc[r][3] + bb4.w);
      *(float4*)&state_out[bn * 64 + o0] = h;
      if constexpr (VAR == 3) {
        *(float4*)&seq_out[(((long long)b * kT + t) * kN + n) * 64 + o0] = h;
      }
      if (t == kT - 1) *(float4*)&last_out[bn * 64 + o0] = h;
    }
  }
}

extern "C" void kernel_launch(void* const* d_in, const int* in_sizes, int n_in, void* d_out,
                              int out_size, void* d_ws, size_t ws_size, hipStream_t stream) {
  (void)in_sizes; (void)n_in; (void)out_size; (void)ws_size;
  const float* x   = (const float*)d_in[0];
  const float* ist = (const float*)d_in[1];
  const float* E   = (const float*)d_in[2];
  const float* gw0 = (const float*)d_in[3];
  const float* gb0 = (const float*)d_in[4];
  const float* uw0 = (const float*)d_in[5];
  const float* ub0 = (const float*)d_in[6];
  const float* gw1 = (const float*)d_in[7];
  const float* gb1 = (const float*)d_in[8];
  const float* uw1 = (const float*)d_in[9];
  const float* ub1 = (const float*)d_in[10];
  float* out = (float*)d_out;

  float* base = (float*)d_ws;
  size_t off = 0;
  auto alloc = [&](size_t elems) {
    float* p = base + off;
    off += (elems + 255) & ~(size_t)255;
    return p;
  };
  float* A   = alloc((size_t)kN * kN);
  float* AT  = alloc((size_t)kN * kN);
  float* Ax  = alloc((size_t)kB * kT * kN * 2);
  float* Wg0 = alloc((size_t)kN * 132 * 128);
  float* Wu0 = alloc((size_t)kN * 132 * 64);
  float* Wg1 = alloc((size_t)kN * 256 * 128);
  float* Wu1 = alloc((size_t)kN * 256 * 64);
  float* Bg0 = alloc((size_t)kN * 128);
  float* Bu0 = alloc((size_t)kN * 64);
  float* Bg1 = alloc((size_t)kN * 128);
  float* Bu1 = alloc((size_t)kN * 64);
  float* s0  = alloc((size_t)kB * kN * kH);
  float* s1  = alloc((size_t)kB * kN * kH);
  float* d1  = alloc((size_t)kB * kN * kH);
  float* d2  = alloc((size_t)kB * kN * kH);
  float* d3  = alloc((size_t)kB * kN * kH);
  float* zr  = alloc((size_t)kB * kN * 128);

  const size_t stateBytes = (size_t)kB * kN * kH * sizeof(float);
  hipMemcpyAsync(s0, ist, stateBytes, hipMemcpyDeviceToDevice, stream);
  hipMemcpyAsync(s1, ist + (size_t)kB * kN * kH, stateBytes, hipMemcpyDeviceToDevice, stream);

  compute_A<<<kN, 256, 0, stream>>>(E, A, AT);
  diffuse_x<<<kB * kT, 256, 0, stream>>>(AT, x, Ax);
  mkw<<<dim3(66, 8), 256, 0, stream>>>(E, gw0, Wg0, 132, 128, 2, 66, 1);
  mkw<<<dim3(33, 8), 256, 0, stream>>>(E, uw0, Wu0, 132, 64, 2, 66, 1);
  mkw<<<dim3(128, 8), 256, 0, stream>>>(E, gw1, Wg1, 256, 128, 2, 128, 0);
  mkw<<<dim3(64, 8), 256, 0, stream>>>(E, uw1, Wu1, 256, 64, 2, 128, 0);
  mkw<<<dim3(1, 8), 256, 0, stream>>>(E, gb0, Bg0, 1, 128, 1, 1, 0);
  mkw<<<dim3(1, 8), 256, 0, stream>>>(E, ub0, Bu0, 1, 64, 1, 1, 0);
  mkw<<<dim3(1, 8), 256, 0, stream>>>(E, gb1, Bg1, 1, 128, 1, 1, 0);
  mkw<<<dim3(1, 8), 256, 0, stream>>>(E, ub1, Bu1, 1, 64, 1, 1, 0);

  for (int t = 0; t < kT; ++t) {
    StepPtrs P{s0, s1, zr, x, Ax, d1, d2, d3};
    // layer 0: gate
    diffuse64<<<dim3(8, kB), 256, 0, stream>>>(A, s0, nullptr, d1);
    gemm_node<0, 128, 132><<<kN, 256, 0, stream>>>(P, Wg0, Bg0, zr, nullptr, nullptr, nullptr, t);
    // layer 0: update (input z*s), writes s0 (= h0_t), last0 at t==T-1
    diffuse64<<<dim3(8, kB), 256, 0, stream>>>(A, s0, zr, d1);
    gemm_node<1, 64, 132><<<kN, 256, 0, stream>>>(P, Wu0, Bu0, nullptr, s0, nullptr,
                                                  out + OUT0, t);
    // layer 1 diffusions: A@h0 (shared), A@s1
    diffuse64<<<dim3(8, kB), 256, 0, stream>>>(A, s0, nullptr, d2);
    diffuse64<<<dim3(8, kB), 256, 0, stream>>>(A, s1, nullptr, d3);
    gemm_node<2, 128, 256><<<kN, 256, 0, stream>>>(P, Wg1, Bg1, zr, nullptr, nullptr, nullptr, t);
    // layer 1 update: A@(z1*s1) overwrites d3
    diffuse64<<<dim3(8, kB), 256, 0, stream>>>(A, s1, zr, d3);
    gemm_node<3, 64, 256><<<kN, 256, 0, stream>>>(P, Wu1, Bu1, nullptr, s1, out,
                                                  out + OUT0 + (size_t)kB * kN * kH, t);
  }
}

// Round 3
// 5946.943 us; speedup vs baseline: 2.7203x; 2.7203x over previous
//
#include <hip/hip_runtime.h>
#include <cmath>

constexpr int kN = 1024;
constexpr int kB = 64;
constexpr int kT = 12;
constexpr int kH = 64;
constexpr int kE = 16;
constexpr long long OUT0 = (long long)kB * kT * kN * kH;  // 50331648
constexpr long long BNH = (long long)kB * kN * kH;        // 4194304

typedef __attribute__((ext_vector_type(8))) __bf16 bf16x8;
typedef __attribute__((ext_vector_type(4))) float f32x4;

struct StepPtrs {
  const float* s0;
  const float* s1;
  const float* zr;
  const float* x;
  const float* ax;
  const float* d1;
  const float* d2;
  const float* d3;
};

__device__ __forceinline__ float sig_(float v) { return 1.f / (1.f + expf(-v)); }

__device__ __forceinline__ unsigned short f2bf(float f) {
  unsigned u = __float_as_uint(f);
  unsigned r = u + 0x7FFFu + ((u >> 16) & 1u);
  return (unsigned short)(r >> 16);
}
__device__ __forceinline__ float bf2f(unsigned short s) {
  return __uint_as_float(((unsigned)s) << 16);
}

__device__ __forceinline__ void gload16(const void* g, void* l) {
  __builtin_amdgcn_global_load_lds((const __attribute__((address_space(1))) void*)g,
                                   (__attribute__((address_space(3))) void*)l, 16, 0, 0);
}

// ---- A = softmax(relu(E E^T), axis=1): writes AT (fp32, for diffuse_x) and
// ---- row-major hi/lo bf16 split Ah/Al (for MFMA diffusion) ----------------
__global__ void __launch_bounds__(256) compute_A(const float* __restrict__ E,
                                                 float* __restrict__ AT,
                                                 unsigned short* __restrict__ Ah,
                                                 unsigned short* __restrict__ Al) {
  int n = blockIdx.x, tx = threadIdx.x;
  __shared__ float En[kE];
  __shared__ float red[4];
  if (tx < kE) En[tx] = E[n * kE + tx];
  __syncthreads();
  float v[4];
  float mx = 0.f;
#pragma unroll
  for (int i = 0; i < 4; ++i) {
    int m = tx + i * 256;
    float s = 0.f;
#pragma unroll
    for (int d = 0; d < kE; ++d) s += En[d] * E[m * kE + d];
    s = fmaxf(s, 0.f);
    v[i] = s;
    mx = fmaxf(mx, s);
  }
#pragma unroll
  for (int off = 32; off; off >>= 1) mx = fmaxf(mx, __shfl_down(mx, off));
  int wid = tx >> 6, lane = tx & 63;
  if (lane == 0) red[wid] = mx;
  __syncthreads();
  mx = fmaxf(fmaxf(red[0], red[1]), fmaxf(red[2], red[3]));
  __syncthreads();
  float sum = 0.f;
#pragma unroll
  for (int i = 0; i < 4; ++i) {
    v[i] = expf(v[i] - mx);
    sum += v[i];
  }
#pragma unroll
  for (int off = 32; off; off >>= 1) sum += __shfl_down(sum, off);
  if (lane == 0) red[wid] = sum;
  __syncthreads();
  sum = red[0] + red[1] + red[2] + red[3];
  float inv = 1.f / sum;
#pragma unroll
  for (int i = 0; i < 4; ++i) {
    int m = tx + i * 256;
    float a = v[i] * inv;
    AT[m * kN + n] = a;
    unsigned short h = f2bf(a);
    Ah[n * kN + m] = h;
    Al[n * kN + m] = f2bf(a - bf2f(h));
  }
}

// ---- per-node weights: out[n][ki][o] = sum_d E[n,d] W[d,k,i,o] -------------
__global__ void __launch_bounds__(256) mkw(const float* __restrict__ E,
                                           const float* __restrict__ Wsrc,
                                           float* __restrict__ out,
                                           int KI, int O, int Kdim, int Idim, int permuteL0) {
  int kio = blockIdx.x * 256 + threadIdx.x;
  int total = KI * O;
  int n0 = blockIdx.y * 128;
  __shared__ float Es[128][kE + 1];
  for (int idx = threadIdx.x; idx < 128 * kE; idx += 256)
    Es[idx >> 4][idx & 15] = E[(n0 + (idx >> 4)) * kE + (idx & 15)];
  __syncthreads();
  if (kio >= total) return;
  int ki = kio / O, o = kio - ki * O;
  int kper = KI / Kdim;
  int k = ki / kper, c = ki - k * kper;
  int i = permuteL0 ? (c < kH ? c + 2 : c - kH) : c;
  float w[kE];
#pragma unroll
  for (int d = 0; d < kE; ++d) w[d] = Wsrc[((d * Kdim + k) * Idim + i) * O + o];
  for (int nn = 0; nn < 128; ++nn) {
    float acc = 0.f;
#pragma unroll
    for (int d = 0; d < kE; ++d) acc += Es[nn][d] * w[d];
    out[(((long long)(n0 + nn)) * KI + ki) * O + o] = acc;
  }
}

// ---- Ax[b,t,n,c] = sum_m A[n,m] x[b,t,m,c], c<2 (one-time) -----------------
__global__ void __launch_bounds__(256) diffuse_x(const float* __restrict__ AT,
                                                 const float* __restrict__ x,
                                                 float* __restrict__ Ax) {
  int bt = blockIdx.x;
  int tx = threadIdx.x;
  float acc[4][2] = {};
  for (int m = 0; m < kN; ++m) {
    float2 xv = *(const float2*)&x[((long long)bt * kN + m) * 2];
#pragma unroll
    for (int i = 0; i < 4; ++i) {
      float a = AT[m * kN + tx + i * 256];
      acc[i][0] += a * xv.x;
      acc[i][1] += a * xv.y;
    }
  }
#pragma unroll
  for (int i = 0; i < 4; ++i) {
    int n = tx + i * 256;
    Ax[((long long)bt * kN + n) * 2 + 0] = acc[i][0];
    Ax[((long long)bt * kN + n) * 2 + 1] = acc[i][1];
  }
}

// ---- prep: V[b,m,c] (opt *mul) -> transposed hi/lo bf16 Vt[colBase+b*64+c][m]
__global__ void __launch_bounds__(256) prep_split(const float* __restrict__ src,
                                                  const float* __restrict__ mul,
                                                  unsigned short* __restrict__ Vth,
                                                  unsigned short* __restrict__ Vtl,
                                                  int colBase) {
  int b = blockIdx.y, m0 = blockIdx.x * 64, tid = threadIdx.x;
  __shared__ float T[64][65];
  for (int idx = tid; idx < 4096; idx += 256) {
    int mi = idx >> 6, c = idx & 63;
    long long rowi = (long long)b * kN + m0 + mi;
    float v = src[rowi * 64 + c];
    if (mul) v *= mul[rowi * 128 + c];
    T[c][mi] = v;
  }
  __syncthreads();
  for (int idx = tid; idx < 4096; idx += 256) {
    int c = idx >> 6, mi = idx & 63;
    float v = T[c][mi];
    unsigned short h = f2bf(v);
    long long o = (long long)(colBase + b * 64 + c) * kN + m0 + mi;
    Vth[o] = h;
    Vtl[o] = f2bf(v - bf2f(h));
  }
}

// ---- diffusion GEMM: out[(bc>>6)*N + n][bc&63] = sum_m A[n,m] V[m,bc] ------
// split-bf16: acc += Ah*Vh + Ah*Vl + Al*Vh. Tile 128(M=n) x 128(N=bc), BK=32.
// 8 waves (2m x 4n), wave tile 64x32 = 4x2 frags of 16x16x32.
// LDS: 4 tiles x 8KB, rows of 64B; chunk swizzle sl^((row>>1)&3) both sides.
__global__ void __launch_bounds__(512) diff_gemm(const unsigned short* __restrict__ Ah,
                                                 const unsigned short* __restrict__ Al,
                                                 const unsigned short* __restrict__ Vth,
                                                 const unsigned short* __restrict__ Vtl,
                                                 float* __restrict__ outp) {
  __shared__ __align__(16) unsigned short lds[16384];
  int tid = threadIdx.x;
  int lane = tid & 63;
  int q = lane >> 4, r16 = lane & 15;
  int wave = tid >> 6;
  int wm = wave >> 2, wn = wave & 3;
  int m0 = blockIdx.y * 128, n0 = blockIdx.x * 128;

  const unsigned short* gsrc[4];
  int ldst[4];
#pragma unroll
  for (int j = 0; j < 4; ++j) {
    int ci = j * 512 + tid;
    int tile = ci >> 9, idx = ci & 511;
    int row = idx >> 2, sp = idx & 3;
    int sl = sp ^ ((row >> 1) & 3);
    const unsigned short* s = (tile == 0) ? Ah : (tile == 1) ? Al : (tile == 2) ? Vth : Vtl;
    int gr = ((tile < 2) ? m0 : n0) + row;
    gsrc[j] = s + (long long)gr * kN + sl * 8;
    ldst[j] = ci * 8;
  }
  int aoff[4][2], voff[2][2];
#pragma unroll
  for (int fm = 0; fm < 4; ++fm) {
    int row = wm * 64 + fm * 16 + r16;
    int s = (q ^ ((row >> 1) & 3)) * 8;
    aoff[fm][0] = row * 32 + s;
    aoff[fm][1] = 4096 + row * 32 + s;
  }
#pragma unroll
  for (int fn = 0; fn < 2; ++fn) {
    int col = wn * 32 + fn * 16 + r16;
    int s = (q ^ ((col >> 1) & 3)) * 8;
    voff[fn][0] = 8192 + col * 32 + s;
    voff[fn][1] = 12288 + col * 32 + s;
  }
  f32x4 acc[4][2];
#pragma unroll
  for (int fm = 0; fm < 4; ++fm)
#pragma unroll
    for (int fn = 0; fn < 2; ++fn) acc[fm][fn] = (f32x4){0.f, 0.f, 0.f, 0.f};

  for (int kt = 0; kt < 32; ++kt) {
    __syncthreads();
#pragma unroll
    for (int j = 0; j < 4; ++j) gload16(gsrc[j] + kt * 32, &lds[ldst[j]]);
    __syncthreads();
    bf16x8 ah[4], al[4], vh[2], vl[2];
#pragma unroll
    for (int fm = 0; fm < 4; ++fm) {
      ah[fm] = *(const bf16x8*)&lds[aoff[fm][0]];
      al[fm] = *(const bf16x8*)&lds[aoff[fm][1]];
    }
#pragma unroll
    for (int fn = 0; fn < 2; ++fn) {
      vh[fn] = *(const bf16x8*)&lds[voff[fn][0]];
      vl[fn] = *(const bf16x8*)&lds[voff[fn][1]];
    }
#pragma unroll
    for (int fm = 0; fm < 4; ++fm)
#pragma unroll
      for (int fn = 0; fn < 2; ++fn) {
        acc[fm][fn] =
            __builtin_amdgcn_mfma_f32_16x16x32_bf16(ah[fm], vh[fn], acc[fm][fn], 0, 0, 0);
        acc[fm][fn] =
            __builtin_amdgcn_mfma_f32_16x16x32_bf16(ah[fm], vl[fn], acc[fm][fn], 0, 0, 0);
        acc[fm][fn] =
            __builtin_amdgcn_mfma_f32_16x16x32_bf16(al[fm], vh[fn], acc[fm][fn], 0, 0, 0);
      }
  }
#pragma unroll
  for (int fm = 0; fm < 4; ++fm)
#pragma unroll
    for (int fn = 0; fn < 2; ++fn) {
      int nrow = m0 + wm * 64 + fm * 16 + q * 4;
      int col = n0 + wn * 32 + fn * 16 + r16;
      long long b = col >> 6;
      int c = col & 63;
#pragma unroll
      for (int r = 0; r < 4; ++r)
        outp[(b * kN + nrow + r) * 64 + c] = acc[fm][fn][r];
    }
}

// ---- per-node GEMM + fused gate epilogue (unchanged from passing round) ----
template <int VAR>
__device__ __forceinline__ float xval(const StepPtrs& P, int b, int n, int ki, int t) {
  long long bn = (long long)b * kN + n;
  if (VAR == 0) {
    if (ki < 64) return P.s0[bn * 64 + ki];
    if (ki < 66) return P.x[(((long long)b * kT + t) * kN + n) * 2 + (ki - 64)];
    if (ki < 130) return P.d1[bn * 64 + (ki - 66)];
    return P.ax[(((long long)b * kT + t) * kN + n) * 2 + (ki - 130)];
  } else if (VAR == 1) {
    if (ki < 64) return P.s0[bn * 64 + ki] * P.zr[bn * 128 + ki];
    if (ki < 66) return P.x[(((long long)b * kT + t) * kN + n) * 2 + (ki - 64)];
    if (ki < 130) return P.d1[bn * 64 + (ki - 66)];
    return P.ax[(((long long)b * kT + t) * kN + n) * 2 + (ki - 130)];
  } else if (VAR == 2) {
    if (ki < 64) return P.s0[bn * 64 + ki];
    if (ki < 128) return P.s1[bn * 64 + (ki - 64)];
    if (ki < 192) return P.d2[bn * 64 + (ki - 128)];
    return P.d3[bn * 64 + (ki - 192)];
  } else {
    if (ki < 64) return P.s0[bn * 64 + ki];
    if (ki < 128) return P.s1[bn * 64 + (ki - 64)] * P.zr[bn * 128 + (ki - 64)];
    if (ki < 192) return P.d2[bn * 64 + (ki - 128)];
    return P.d3[bn * 64 + (ki - 192)];
  }
}

template <int VAR, int O, int KC>
__global__ void __launch_bounds__(256) gemm_node(StepPtrs P, const float* __restrict__ W,
                                                 const float* __restrict__ bias,
                                                 float* __restrict__ zr_out,
                                                 float* __restrict__ state_out,
                                                 float* __restrict__ seq_out,
                                                 float* __restrict__ last_out, int t) {
  constexpr int OG = O / 4;
  constexpr int BG = 256 / OG;
  constexpr int TB = 64 / BG;
  constexpr int NKT = (KC + 31) / 32;
  int n = blockIdx.x;
  int tx = threadIdx.x;
  int og = tx % OG, bg = tx / OG;
  int o0 = og * 4, b0 = bg * TB;
  __shared__ float Xs[32][68];
  __shared__ float Ws[32][O];
  float acc[TB][4] = {};
  for (int kt = 0; kt < NKT; ++kt) {
    int kbase = kt * 32;
    for (int idx = tx; idx < 2048; idx += 256) {
      int bb = idx >> 5, kk = idx & 31;
      int kig = kbase + kk;
      Xs[kk][bb] = (kig < KC) ? xval<VAR>(P, bb, n, kig, t) : 0.f;
    }
    for (int idx = tx; idx < 32 * O; idx += 256) {
      int kk = idx / O, oo = idx - kk * O;
      int kig = kbase + kk;
      Ws[kk][oo] = (kig < KC) ? W[((long long)n * KC + kig) * O + oo] : 0.f;
    }
    __syncthreads();
#pragma unroll 4
    for (int kk = 0; kk < 32; ++kk) {
      float4 wv = *(const float4*)&Ws[kk][o0];
      float xv[TB];
#pragma unroll
      for (int r = 0; r < TB; r += 4) {
        float4 xq = *(const float4*)&Xs[kk][b0 + r];
        xv[r] = xq.x; xv[r + 1] = xq.y; xv[r + 2] = xq.z; xv[r + 3] = xq.w;
      }
#pragma unroll
      for (int r = 0; r < TB; ++r) {
        acc[r][0] += xv[r] * wv.x;
        acc[r][1] += xv[r] * wv.y;
        acc[r][2] += xv[r] * wv.z;
        acc[r][3] += xv[r] * wv.w;
      }
    }
    __syncthreads();
  }
  if constexpr (O == 128) {
    float4 bb4 = *(const float4*)&bias[n * 128 + o0];
#pragma unroll
    for (int r = 0; r < TB; ++r) {
      long long bn = (long long)(b0 + r) * kN + n;
      float4 res;
      res.x = sig_(acc[r][0] + bb4.x);
      res.y = sig_(acc[r][1] + bb4.y);
      res.z = sig_(acc[r][2] + bb4.z);
      res.w = sig_(acc[r][3] + bb4.w);
      *(float4*)&zr_out[bn * 128 + o0] = res;
    }
  } else {
    const float* sptr = (VAR == 1) ? P.s0 : P.s1;
    float4 bb4 = *(const float4*)&bias[n * 64 + o0];
#pragma unroll
    for (int r = 0; r < TB; ++r) {
      int b = b0 + r;
      long long bn = (long long)b * kN + n;
      float4 rr = *(const float4*)&P.zr[bn * 128 + 64 + o0];
      float4 ss = *(const float4*)&sptr[bn * 64 + o0];
      float4 h;
      h.x = rr.x * ss.x + (1.f - rr.x) * tanhf(acc[r][0] + bb4.x);
      h.y = rr.y * ss.y + (1.f - rr.y) * tanhf(acc[r][1] + bb4.y);
      h.z = rr.z * ss.z + (1.f - rr.z) * tanhf(acc[r][2] + bb4.z);
      h.w = rr.w * ss.w + (1.f - rr.w) * tanhf(acc[r][3] + bb4.w);
      *(float4*)&state_out[bn * 64 + o0] = h;
      if constexpr (VAR == 3) {
        *(float4*)&seq_out[(((long long)b * kT + t) * kN + n) * 64 + o0] = h;
      }
      if (t == kT - 1) *(float4*)&last_out[bn * 64 + o0] = h;
    }
  }
}

extern "C" void kernel_launch(void* const* d_in, const int* in_sizes, int n_in, void* d_out,
                              int out_size, void* d_ws, size_t ws_size, hipStream_t stream) {
  (void)in_sizes; (void)n_in; (void)out_size; (void)ws_size;
  const float* x   = (const float*)d_in[0];
  const float* ist = (const float*)d_in[1];
  const float* E   = (const float*)d_in[2];
  const float* gw0 = (const float*)d_in[3];
  const float* gb0 = (const float*)d_in[4];
  const float* uw0 = (const float*)d_in[5];
  const float* ub0 = (const float*)d_in[6];
  const float* gw1 = (const float*)d_in[7];
  const float* gb1 = (const float*)d_in[8];
  const float* uw1 = (const float*)d_in[9];
  const float* ub1 = (const float*)d_in[10];
  float* out = (float*)d_out;

  char* base = (char*)d_ws;
  size_t off = 0;
  auto alloc = [&](size_t bytes) {
    char* p = base + off;
    off += (bytes + 1023) & ~(size_t)1023;
    return p;
  };
  unsigned short* Vth = (unsigned short*)alloc((size_t)8192 * kN * 2);
  unsigned short* Vtl = (unsigned short*)alloc((size_t)8192 * kN * 2);
  float* AT = (float*)Vth;  // alias: AT used only by diffuse_x before any prep
  unsigned short* Ahh = (unsigned short*)alloc((size_t)kN * kN * 2);
  unsigned short* All = (unsigned short*)alloc((size_t)kN * kN * 2);
  float* Ax  = (float*)alloc((size_t)kB * kT * kN * 2 * 4);
  float* Wg0 = (float*)alloc((size_t)kN * 132 * 128 * 4);
  float* Wu0 = (float*)alloc((size_t)kN * 132 * 64 * 4);
  float* Wg1 = (float*)alloc((size_t)kN * 256 * 128 * 4);
  float* Wu1 = (float*)alloc((size_t)kN * 256 * 64 * 4);
  float* Bg0 = (float*)alloc((size_t)kN * 128 * 4);
  float* Bu0 = (float*)alloc((size_t)kN * 64 * 4);
  float* Bg1 = (float*)alloc((size_t)kN * 128 * 4);
  float* Bu1 = (float*)alloc((size_t)kN * 64 * 4);
  float* s0  = (float*)alloc((size_t)BNH * 4);
  float* s1  = (float*)alloc((size_t)BNH * 4);
  float* dx  = (float*)alloc((size_t)BNH * 4);        // shared by G1-out and G3-out
  float* dd  = (float*)alloc((size_t)BNH * 2 * 4);    // [d2 | d3] contiguous
  float* zr  = (float*)alloc((size_t)kB * kN * 128 * 4);
  float* d2 = dd;
  float* d3 = dd + BNH;

  const size_t stateBytes = (size_t)BNH * sizeof(float);
  (void)hipMemcpyAsync(s0, ist, stateBytes, hipMemcpyDeviceToDevice, stream);
  (void)hipMemcpyAsync(s1, ist + BNH, stateBytes, hipMemcpyDeviceToDevice, stream);

  compute_A<<<kN, 256, 0, stream>>>(E, AT, Ahh, All);
  diffuse_x<<<kB * kT, 256, 0, stream>>>(AT, x, Ax);
  mkw<<<dim3(66, 8), 256, 0, stream>>>(E, gw0, Wg0, 132, 128, 2, 66, 1);
  mkw<<<dim3(33, 8), 256, 0, stream>>>(E, uw0, Wu0, 132, 64, 2, 66, 1);
  mkw<<<dim3(128, 8), 256, 0, stream>>>(E, gw1, Wg1, 256, 128, 2, 128, 0);
  mkw<<<dim3(64, 8), 256, 0, stream>>>(E, uw1, Wu1, 256, 64, 2, 128, 0);
  mkw<<<dim3(1, 8), 256, 0, stream>>>(E, gb0, Bg0, 1, 128, 1, 1, 0);
  mkw<<<dim3(1, 8), 256, 0, stream>>>(E, ub0, Bu0, 1, 64, 1, 1, 0);
  mkw<<<dim3(1, 8), 256, 0, stream>>>(E, gb1, Bg1, 1, 128, 1, 1, 0);
  mkw<<<dim3(1, 8), 256, 0, stream>>>(E, ub1, Bu1, 1, 64, 1, 1, 0);

  // bootstrap: d2 = A @ s0_init (reused as "A @ s0_prev" by step 0's L0 gate)
  prep_split<<<dim3(16, kB), 256, 0, stream>>>(s0, nullptr, Vth, Vtl, 0);
  diff_gemm<<<dim3(32, 8), 512, 0, stream>>>(Ahh, All, Vth, Vtl, d2);

  for (int t = 0; t < kT; ++t) {
    // L0 gate (diffused state = d2 from previous step / bootstrap)
    StepPtrs Pg0{s0, s1, zr, x, Ax, d2, d2, d3};
    gemm_node<0, 128, 132><<<kN, 256, 0, stream>>>(Pg0, Wg0, Bg0, zr, nullptr, nullptr, nullptr, t);
    // G1 = A @ (z0*s0) -> dx
    prep_split<<<dim3(16, kB), 256, 0, stream>>>(s0, zr, Vth, Vtl, 0);
    diff_gemm<<<dim3(32, 8), 512, 0, stream>>>(Ahh, All, Vth, Vtl, dx);
    // L0 update: s0 <- h0; lasts[0] at t==T-1
    StepPtrs Pu0{s0, s1, zr, x, Ax, dx, d2, d3};
    gemm_node<1, 64, 132><<<kN, 256, 0, stream>>>(Pu0, Wu0, Bu0, nullptr, s0, nullptr,
                                                  out + OUT0, t);
    // G2 = A @ [h0 ; s1] -> [d2 | d3]   (d2 also feeds next step's L0 gate)
    prep_split<<<dim3(16, kB), 256, 0, stream>>>(s0, nullptr, Vth, Vtl, 0);
    prep_split<<<dim3(16, kB), 256, 0, stream>>>(s1, nullptr, Vth, Vtl, 4096);
    diff_gemm<<<dim3(64, 8), 512, 0, stream>>>(Ahh, All, Vth, Vtl, d2);
    // L1 gate
    StepPtrs P1g{s0, s1, zr, x, Ax, d2, d2, d3};
    gemm_node<2, 128, 256><<<kN, 256, 0, stream>>>(P1g, Wg1, Bg1, zr, nullptr, nullptr, nullptr, t);
    // G3 = A @ (z1*s1) -> dx
    prep_split<<<dim3(16, kB), 256, 0, stream>>>(s1, zr, Vth, Vtl, 0);
    diff_gemm<<<dim3(32, 8), 512, 0, stream>>>(Ahh, All, Vth, Vtl, dx);
    // L1 update: s1 <- h1; seq out; lasts[1] at t==T-1
    StepPtrs P1u{s0, s1, zr, x, Ax, d2, d2, dx};
    gemm_node<3, 64, 256><<<kN, 256, 0, stream>>>(P1u, Wu1, Bu1, nullptr, s1, out,
                                                  out + OUT0 + BNH, t);
  }
}

// Round 4
// 5620.959 us; speedup vs baseline: 2.8781x; 1.0580x over previous
//
#include <hip/hip_runtime.h>
#include <cmath>

constexpr int kN = 1024;
constexpr int kB = 64;
constexpr int kT = 12;
constexpr int kH = 64;
constexpr int kE = 16;
constexpr long long OUT0 = (long long)kB * kT * kN * kH;  // 50331648
constexpr long long BNH = (long long)kB * kN * kH;        // 4194304

typedef __attribute__((ext_vector_type(8))) __bf16 bf16x8;
typedef __attribute__((ext_vector_type(4))) float f32x4;

struct StepPtrs {
  const float* s0;
  const float* s1;
  const float* zr;
  const float* x;
  const float* ax;
  const float* d1;
  const float* d2;
  const float* d3;
};

__device__ __forceinline__ float sig_(float v) { return 1.f / (1.f + expf(-v)); }

__device__ __forceinline__ unsigned short f2bf(float f) {
  unsigned u = __float_as_uint(f);
  unsigned r = u + 0x7FFFu + ((u >> 16) & 1u);
  return (unsigned short)(r >> 16);
}
__device__ __forceinline__ float bf2f(unsigned short s) {
  return __uint_as_float(((unsigned)s) << 16);
}

__device__ __forceinline__ void gload16(const void* g, void* l) {
  __builtin_amdgcn_global_load_lds((const __attribute__((address_space(1))) void*)g,
                                   (__attribute__((address_space(3))) void*)l, 16, 0, 0);
}

// ---- A = softmax(relu(E E^T), axis=1): AT (fp32) + hi/lo bf16 split --------
__global__ void __launch_bounds__(256) compute_A(const float* __restrict__ E,
                                                 float* __restrict__ AT,
                                                 unsigned short* __restrict__ Ah,
                                                 unsigned short* __restrict__ Al) {
  int n = blockIdx.x, tx = threadIdx.x;
  __shared__ float En[kE];
  __shared__ float red[4];
  if (tx < kE) En[tx] = E[n * kE + tx];
  __syncthreads();
  float v[4];
  float mx = 0.f;
#pragma unroll
  for (int i = 0; i < 4; ++i) {
    int m = tx + i * 256;
    float s = 0.f;
#pragma unroll
    for (int d = 0; d < kE; ++d) s += En[d] * E[m * kE + d];
    s = fmaxf(s, 0.f);
    v[i] = s;
    mx = fmaxf(mx, s);
  }
#pragma unroll
  for (int off = 32; off; off >>= 1) mx = fmaxf(mx, __shfl_down(mx, off));
  int wid = tx >> 6, lane = tx & 63;
  if (lane == 0) red[wid] = mx;
  __syncthreads();
  mx = fmaxf(fmaxf(red[0], red[1]), fmaxf(red[2], red[3]));
  __syncthreads();
  float sum = 0.f;
#pragma unroll
  for (int i = 0; i < 4; ++i) {
    v[i] = expf(v[i] - mx);
    sum += v[i];
  }
#pragma unroll
  for (int off = 32; off; off >>= 1) sum += __shfl_down(sum, off);
  if (lane == 0) red[wid] = sum;
  __syncthreads();
  sum = red[0] + red[1] + red[2] + red[3];
  float inv = 1.f / sum;
#pragma unroll
  for (int i = 0; i < 4; ++i) {
    int m = tx + i * 256;
    float a = v[i] * inv;
    AT[m * kN + n] = a;
    unsigned short h = f2bf(a);
    Ah[n * kN + m] = h;
    Al[n * kN + m] = f2bf(a - bf2f(h));
  }
}

// ---- per-node weights: out[n][ki][o] = sum_d E[n,d] W[d,k,i,o] -------------
__global__ void __launch_bounds__(256) mkw(const float* __restrict__ E,
                                           const float* __restrict__ Wsrc,
                                           float* __restrict__ out,
                                           int KI, int O, int Kdim, int Idim, int permuteL0) {
  int kio = blockIdx.x * 256 + threadIdx.x;
  int total = KI * O;
  int n0 = blockIdx.y * 128;
  __shared__ float Es[128][kE + 1];
  for (int idx = threadIdx.x; idx < 128 * kE; idx += 256)
    Es[idx >> 4][idx & 15] = E[(n0 + (idx >> 4)) * kE + (idx & 15)];
  __syncthreads();
  if (kio >= total) return;
  int ki = kio / O, o = kio - ki * O;
  int kper = KI / Kdim;
  int k = ki / kper, c = ki - k * kper;
  int i = permuteL0 ? (c < kH ? c + 2 : c - kH) : c;
  float w[kE];
#pragma unroll
  for (int d = 0; d < kE; ++d) w[d] = Wsrc[((d * Kdim + k) * Idim + i) * O + o];
  for (int nn = 0; nn < 128; ++nn) {
    float acc = 0.f;
#pragma unroll
    for (int d = 0; d < kE; ++d) acc += Es[nn][d] * w[d];
    out[(((long long)(n0 + nn)) * KI + ki) * O + o] = acc;
  }
}

// ---- Ax[bt,n,c] = sum_m A[n,m] x[bt,m,c]; 4 bt per block (A reuse) ---------
__global__ void __launch_bounds__(256) diffuse_x(const float* __restrict__ AT,
                                                 const float* __restrict__ x,
                                                 float* __restrict__ Ax) {
  int bt0 = blockIdx.x * 4;
  int tx = threadIdx.x;
  float acc[4][4][2] = {};
  for (int m = 0; m < kN; ++m) {
    float a[4];
#pragma unroll
    for (int i = 0; i < 4; ++i) a[i] = AT[m * kN + tx + i * 256];
#pragma unroll
    for (int j = 0; j < 4; ++j) {
      float2 xv = *(const float2*)&x[((long long)(bt0 + j) * kN + m) * 2];
#pragma unroll
      for (int i = 0; i < 4; ++i) {
        acc[i][j][0] += a[i] * xv.x;
        acc[i][j][1] += a[i] * xv.y;
      }
    }
  }
#pragma unroll
  for (int i = 0; i < 4; ++i)
#pragma unroll
    for (int j = 0; j < 4; ++j) {
      int n = tx + i * 256;
      float2 r = make_float2(acc[i][j][0], acc[i][j][1]);
      *(float2*)&Ax[((long long)(bt0 + j) * kN + n) * 2] = r;
    }
}

// ---- prep: V[b,m,c] (opt *mul) -> transposed hi/lo bf16 Vt[z*4096+b*64+c][m]
// blockIdx.z selects source (srcA / srcB) for merged launches.
__global__ void __launch_bounds__(256) prep_split(const float* __restrict__ srcA,
                                                  const float* __restrict__ srcB,
                                                  const float* __restrict__ mul,
                                                  unsigned short* __restrict__ Vth,
                                                  unsigned short* __restrict__ Vtl) {
  int b = blockIdx.y, m0 = blockIdx.x * 64, tid = threadIdx.x;
  int z = blockIdx.z;
  const float* src = z ? srcB : srcA;
  int colBase = z * 4096;
  __shared__ float T[64][65];
  for (int idx = tid; idx < 1024; idx += 256) {
    int mi = idx >> 4, c4 = (idx & 15) * 4;
    long long rowi = (long long)b * kN + m0 + mi;
    float4 v = *(const float4*)&src[rowi * 64 + c4];
    if (mul) {
      float4 mz = *(const float4*)&mul[rowi * 128 + c4];
      v.x *= mz.x; v.y *= mz.y; v.z *= mz.z; v.w *= mz.w;
    }
    T[c4 + 0][mi] = v.x;
    T[c4 + 1][mi] = v.y;
    T[c4 + 2][mi] = v.z;
    T[c4 + 3][mi] = v.w;
  }
  __syncthreads();
  for (int idx = tid; idx < 1024; idx += 256) {
    int c = idx >> 4, mi4 = (idx & 15) * 4;
    float4 v = *(const float4*)&T[c][mi4];
    ushort4 h, l;
    h.x = f2bf(v.x); l.x = f2bf(v.x - bf2f(h.x));
    h.y = f2bf(v.y); l.y = f2bf(v.y - bf2f(h.y));
    h.z = f2bf(v.z); l.z = f2bf(v.z - bf2f(h.z));
    h.w = f2bf(v.w); l.w = f2bf(v.w - bf2f(h.w));
    long long o = (long long)(colBase + b * 64 + c) * kN + m0 + mi4;
    *(ushort4*)&Vth[o] = h;
    *(ushort4*)&Vtl[o] = l;
  }
}

// ---- diffusion GEMM (2-phase double-buffered pipeline) ---------------------
// out[(bc>>6)*N + n][bc&63] = sum_m A[n,m] V[m,bc]; acc += Ah*Vh+Ah*Vl+Al*Vh.
// Tile 128x128, BK=32; 8 waves (2m x 4n), wave tile 64x32 = 4x2 frags 16x16x32.
// LDS: 2 buffers x (4 tiles x 8KB); chunk swizzle sl^((row>>1)&3) both sides.
__global__ void __launch_bounds__(512, 4) diff_gemm(const unsigned short* __restrict__ Ah,
                                                    const unsigned short* __restrict__ Al,
                                                    const unsigned short* __restrict__ Vth,
                                                    const unsigned short* __restrict__ Vtl,
                                                    float* __restrict__ outp) {
  __shared__ __align__(16) unsigned short lds[2][16384];
  int tid = threadIdx.x;
  int lane = tid & 63;
  int q = lane >> 4, r16 = lane & 15;
  int wave = tid >> 6;
  int wm = wave >> 2, wn = wave & 3;
  int m0 = blockIdx.y * 128, n0 = blockIdx.x * 128;

  const unsigned short* gsrc[4];
  int ldst[4];
#pragma unroll
  for (int j = 0; j < 4; ++j) {
    int ci = j * 512 + tid;
    int tile = ci >> 9, idx = ci & 511;
    int row = idx >> 2, sp = idx & 3;
    int sl = sp ^ ((row >> 1) & 3);
    const unsigned short* s = (tile == 0) ? Ah : (tile == 1) ? Al : (tile == 2) ? Vth : Vtl;
    int gr = ((tile < 2) ? m0 : n0) + row;
    gsrc[j] = s + (long long)gr * kN + sl * 8;
    ldst[j] = ci * 8;
  }
  int aoff[4][2], voff[2][2];
#pragma unroll
  for (int fm = 0; fm < 4; ++fm) {
    int row = wm * 64 + fm * 16 + r16;
    int s = (q ^ ((row >> 1) & 3)) * 8;
    aoff[fm][0] = row * 32 + s;
    aoff[fm][1] = 4096 + row * 32 + s;
  }
#pragma unroll
  for (int fn = 0; fn < 2; ++fn) {
    int col = wn * 32 + fn * 16 + r16;
    int s = (q ^ ((col >> 1) & 3)) * 8;
    voff[fn][0] = 8192 + col * 32 + s;
    voff[fn][1] = 12288 + col * 32 + s;
  }
  f32x4 acc[4][2];
#pragma unroll
  for (int fm = 0; fm < 4; ++fm)
#pragma unroll
    for (int fn = 0; fn < 2; ++fn) acc[fm][fn] = (f32x4){0.f, 0.f, 0.f, 0.f};

  auto STAGE = [&](int buf, int kt) {
#pragma unroll
    for (int j = 0; j < 4; ++j) gload16(gsrc[j] + kt * 32, &lds[buf][ldst[j]]);
  };
  auto COMPUTE = [&](int buf) {
    const unsigned short* L = &lds[buf][0];
    bf16x8 ah[4], al[4], vh[2], vl[2];
#pragma unroll
    for (int fm = 0; fm < 4; ++fm) {
      ah[fm] = *(const bf16x8*)&L[aoff[fm][0]];
      al[fm] = *(const bf16x8*)&L[aoff[fm][1]];
    }
#pragma unroll
    for (int fn = 0; fn < 2; ++fn) {
      vh[fn] = *(const bf16x8*)&L[voff[fn][0]];
      vl[fn] = *(const bf16x8*)&L[voff[fn][1]];
    }
#pragma unroll
    for (int fm = 0; fm < 4; ++fm)
#pragma unroll
      for (int fn = 0; fn < 2; ++fn) {
        acc[fm][fn] =
            __builtin_amdgcn_mfma_f32_16x16x32_bf16(ah[fm], vh[fn], acc[fm][fn], 0, 0, 0);
        acc[fm][fn] =
            __builtin_amdgcn_mfma_f32_16x16x32_bf16(ah[fm], vl[fn], acc[fm][fn], 0, 0, 0);
        acc[fm][fn] =
            __builtin_amdgcn_mfma_f32_16x16x32_bf16(al[fm], vh[fn], acc[fm][fn], 0, 0, 0);
      }
  };

  STAGE(0, 0);
  asm volatile("s_waitcnt vmcnt(0)" ::: "memory");
  __builtin_amdgcn_s_barrier();
#pragma unroll 1
  for (int kt = 0; kt < 30; kt += 2) {
    STAGE(1, kt + 1);
    COMPUTE(0);
    asm volatile("s_waitcnt vmcnt(0)" ::: "memory");
    __builtin_amdgcn_s_barrier();
    STAGE(0, kt + 2);
    COMPUTE(1);
    asm volatile("s_waitcnt vmcnt(0)" ::: "memory");
    __builtin_amdgcn_s_barrier();
  }
  STAGE(1, 31);
  COMPUTE(0);
  asm volatile("s_waitcnt vmcnt(0)" ::: "memory");
  __builtin_amdgcn_s_barrier();
  COMPUTE(1);

#pragma unroll
  for (int fm = 0; fm < 4; ++fm)
#pragma unroll
    for (int fn = 0; fn < 2; ++fn) {
      int nrow = m0 + wm * 64 + fm * 16 + q * 4;
      int col = n0 + wn * 32 + fn * 16 + r16;
      long long b = col >> 6;
      int c = col & 63;
#pragma unroll
      for (int r = 0; r < 4; ++r)
        outp[(b * kN + nrow + r) * 64 + c] = acc[fm][fn][r];
    }
}

// ---- per-node GEMM + fused gate epilogue -----------------------------------
template <int VAR>
__device__ __forceinline__ float xval(const StepPtrs& P, int b, int n, int ki, int t) {
  long long bn = (long long)b * kN + n;
  if (VAR == 0) {
    if (ki < 64) return P.s0[bn * 64 + ki];
    if (ki < 66) return P.x[(((long long)b * kT + t) * kN + n) * 2 + (ki - 64)];
    if (ki < 130) return P.d1[bn * 64 + (ki - 66)];
    return P.ax[(((long long)b * kT + t) * kN + n) * 2 + (ki - 130)];
  } else if (VAR == 1) {
    if (ki < 64) return P.s0[bn * 64 + ki] * P.zr[bn * 128 + ki];
    if (ki < 66) return P.x[(((long long)b * kT + t) * kN + n) * 2 + (ki - 64)];
    if (ki < 130) return P.d1[bn * 64 + (ki - 66)];
    return P.ax[(((long long)b * kT + t) * kN + n) * 2 + (ki - 130)];
  } else if (VAR == 2) {
    if (ki < 64) return P.s0[bn * 64 + ki];
    if (ki < 128) return P.s1[bn * 64 + (ki - 64)];
    if (ki < 192) return P.d2[bn * 64 + (ki - 128)];
    return P.d3[bn * 64 + (ki - 192)];
  } else {
    if (ki < 64) return P.s0[bn * 64 + ki];
    if (ki < 128) return P.s1[bn * 64 + (ki - 64)] * P.zr[bn * 128 + (ki - 64)];
    if (ki < 192) return P.d2[bn * 64 + (ki - 128)];
    return P.d3[bn * 64 + (ki - 192)];
  }
}

template <int VAR, int O, int KC>
__global__ void __launch_bounds__(256) gemm_node(StepPtrs P, const float* __restrict__ W,
                                                 const float* __restrict__ bias,
                                                 float* __restrict__ zr_out,
                                                 float* __restrict__ state_out,
                                                 float* __restrict__ seq_out,
                                                 float* __restrict__ last_out, int t) {
  constexpr int OG = O / 4;
  constexpr int BG = 256 / OG;
  constexpr int TB = 64 / BG;
  constexpr int NKT = (KC + 31) / 32;
  int n = blockIdx.x;
  int tx = threadIdx.x;
  int og = tx % OG, bg = tx / OG;
  int o0 = og * 4, b0 = bg * TB;
  __shared__ float Xs[32][68];
  __shared__ float Ws[32][O];
  float acc[TB][4] = {};
  for (int kt = 0; kt < NKT; ++kt) {
    int kbase = kt * 32;
    for (int idx = tx; idx < 2048; idx += 256) {
      int bb = idx >> 5, kk = idx & 31;
      int kig = kbase + kk;
      Xs[kk][bb] = (kig < KC) ? xval<VAR>(P, bb, n, kig, t) : 0.f;
    }
    for (int idx = tx; idx < 32 * O; idx += 256) {
      int kk = idx / O, oo = idx - kk * O;
      int kig = kbase + kk;
      Ws[kk][oo] = (kig < KC) ? W[((long long)n * KC + kig) * O + oo] : 0.f;
    }
    __syncthreads();
#pragma unroll 4
    for (int kk = 0; kk < 32; ++kk) {
      float4 wv = *(const float4*)&Ws[kk][o0];
      float xv[TB];
#pragma unroll
      for (int r = 0; r < TB; r += 4) {
        float4 xq = *(const float4*)&Xs[kk][b0 + r];
        xv[r] = xq.x; xv[r + 1] = xq.y; xv[r + 2] = xq.z; xv[r + 3] = xq.w;
      }
#pragma unroll
      for (int r = 0; r < TB; ++r) {
        acc[r][0] += xv[r] * wv.x;
        acc[r][1] += xv[r] * wv.y;
        acc[r][2] += xv[r] * wv.z;
        acc[r][3] += xv[r] * wv.w;
      }
    }
    __syncthreads();
  }
  if constexpr (O == 128) {
    float4 bb4 = *(const float4*)&bias[n * 128 + o0];
#pragma unroll
    for (int r = 0; r < TB; ++r) {
      long long bn = (long long)(b0 + r) * kN + n;
      float4 res;
      res.x = sig_(acc[r][0] + bb4.x);
      res.y = sig_(acc[r][1] + bb4.y);
      res.z = sig_(acc[r][2] + bb4.z);
      res.w = sig_(acc[r][3] + bb4.w);
      *(float4*)&zr_out[bn * 128 + o0] = res;
    }
  } else {
    const float* sptr = (VAR == 1) ? P.s0 : P.s1;
    float4 bb4 = *(const float4*)&bias[n * 64 + o0];
#pragma unroll
    for (int r = 0; r < TB; ++r) {
      int b = b0 + r;
      long long bn = (long long)b * kN + n;
      float4 rr = *(const float4*)&P.zr[bn * 128 + 64 + o0];
      float4 ss = *(const float4*)&sptr[bn * 64 + o0];
      float4 h;
      h.x = rr.x * ss.x + (1.f - rr.x) * tanhf(acc[r][0] + bb4.x);
      h.y = rr.y * ss.y + (1.f - rr.y) * tanhf(acc[r][1] + bb4.y);
      h.z = rr.z * ss.z + (1.f - rr.z) * tanhf(acc[r][2] + bb4.z);
      h.w = rr.w * ss.w + (1.f - rr.w) * tanhf(acc[r][3] + bb4.w);
      *(float4*)&state_out[bn * 64 + o0] = h;
      if constexpr (VAR == 3) {
        *(float4*)&seq_out[(((long long)b * kT + t) * kN + n) * 64 + o0] = h;
      }
      if (t == kT - 1) *(float4*)&last_out[bn * 64 + o0] = h;
    }
  }
}

extern "C" void kernel_launch(void* const* d_in, const int* in_sizes, int n_in, void* d_out,
                              int out_size, void* d_ws, size_t ws_size, hipStream_t stream) {
  (void)in_sizes; (void)n_in; (void)out_size; (void)ws_size;
  const float* x   = (const float*)d_in[0];
  const float* ist = (const float*)d_in[1];
  const float* E   = (const float*)d_in[2];
  const float* gw0 = (const float*)d_in[3];
  const float* gb0 = (const float*)d_in[4];
  const float* uw0 = (const float*)d_in[5];
  const float* ub0 = (const float*)d_in[6];
  const float* gw1 = (const float*)d_in[7];
  const float* gb1 = (const float*)d_in[8];
  const float* uw1 = (const float*)d_in[9];
  const float* ub1 = (const float*)d_in[10];
  float* out = (float*)d_out;

  char* base = (char*)d_ws;
  size_t off = 0;
  auto alloc = [&](size_t bytes) {
    char* p = base + off;
    off += (bytes + 1023) & ~(size_t)1023;
    return p;
  };
  unsigned short* Vth = (unsigned short*)alloc((size_t)8192 * kN * 2);
  unsigned short* Vtl = (unsigned short*)alloc((size_t)8192 * kN * 2);
  float* AT = (float*)Vth;  // alias: AT used only by diffuse_x before any prep
  unsigned short* Ahh = (unsigned short*)alloc((size_t)kN * kN * 2);
  unsigned short* All = (unsigned short*)alloc((size_t)kN * kN * 2);
  float* Ax  = (float*)alloc((size_t)kB * kT * kN * 2 * 4);
  float* Wg0 = (float*)alloc((size_t)kN * 132 * 128 * 4);
  float* Wu0 = (float*)alloc((size_t)kN * 132 * 64 * 4);
  float* Wg1 = (float*)alloc((size_t)kN * 256 * 128 * 4);
  float* Wu1 = (float*)alloc((size_t)kN * 256 * 64 * 4);
  float* Bg0 = (float*)alloc((size_t)kN * 128 * 4);
  float* Bu0 = (float*)alloc((size_t)kN * 64 * 4);
  float* Bg1 = (float*)alloc((size_t)kN * 128 * 4);
  float* Bu1 = (float*)alloc((size_t)kN * 64 * 4);
  float* s0  = (float*)alloc((size_t)BNH * 4);
  float* s1  = (float*)alloc((size_t)BNH * 4);
  float* dx  = (float*)alloc((size_t)BNH * 4);
  float* dd  = (float*)alloc((size_t)BNH * 2 * 4);  // [d2 | d3] contiguous
  float* zr  = (float*)alloc((size_t)kB * kN * 128 * 4);
  float* d2 = dd;
  float* d3 = dd + BNH;

  const size_t stateBytes = (size_t)BNH * sizeof(float);
  (void)hipMemcpyAsync(s0, ist, stateBytes, hipMemcpyDeviceToDevice, stream);
  (void)hipMemcpyAsync(s1, ist + BNH, stateBytes, hipMemcpyDeviceToDevice, stream);

  compute_A<<<kN, 256, 0, stream>>>(E, AT, Ahh, All);
  diffuse_x<<<kB * kT / 4, 256, 0, stream>>>(AT, x, Ax);
  mkw<<<dim3(66, 8), 256, 0, stream>>>(E, gw0, Wg0, 132, 128, 2, 66, 1);
  mkw<<<dim3(33, 8), 256, 0, stream>>>(E, uw0, Wu0, 132, 64, 2, 66, 1);
  mkw<<<dim3(128, 8), 256, 0, stream>>>(E, gw1, Wg1, 256, 128, 2, 128, 0);
  mkw<<<dim3(64, 8), 256, 0, stream>>>(E, uw1, Wu1, 256, 64, 2, 128, 0);
  mkw<<<dim3(1, 8), 256, 0, stream>>>(E, gb0, Bg0, 1, 128, 1, 1, 0);
  mkw<<<dim3(1, 8), 256, 0, stream>>>(E, ub0, Bu0, 1, 64, 1, 1, 0);
  mkw<<<dim3(1, 8), 256, 0, stream>>>(E, gb1, Bg1, 1, 128, 1, 1, 0);
  mkw<<<dim3(1, 8), 256, 0, stream>>>(E, ub1, Bu1, 1, 64, 1, 1, 0);

  // bootstrap: d2 = A @ s0_init (step 0's L0 gate reads it as A @ s0_prev)
  prep_split<<<dim3(16, kB, 1), 256, 0, stream>>>(s0, nullptr, nullptr, Vth, Vtl);
  diff_gemm<<<dim3(32, 8), 512, 0, stream>>>(Ahh, All, Vth, Vtl, d2);

  for (int t = 0; t < kT; ++t) {
    // L0 gate (diffused state = d2 from previous step / bootstrap)
    StepPtrs Pg0{s0, s1, zr, x, Ax, d2, d2, d3};
    gemm_node<0, 128, 132><<<kN, 256, 0, stream>>>(Pg0, Wg0, Bg0, zr, nullptr, nullptr, nullptr, t);
    // G1 = A @ (z0*s0) -> dx
    prep_split<<<dim3(16, kB, 1), 256, 0, stream>>>(s0, nullptr, zr, Vth, Vtl);
    diff_gemm<<<dim3(32, 8), 512, 0, stream>>>(Ahh, All, Vth, Vtl, dx);
    // L0 update: s0 <- h0; lasts[0] at t==T-1
    StepPtrs Pu0{s0, s1, zr, x, Ax, dx, d2, d3};
    gemm_node<1, 64, 132><<<kN, 256, 0, stream>>>(Pu0, Wu0, Bu0, nullptr, s0, nullptr,
                                                  out + OUT0, t);
    // G2 = A @ [h0 ; s1] -> [d2 | d3]   (d2 also feeds next step's L0 gate)
    prep_split<<<dim3(16, kB, 2), 256, 0, stream>>>(s0, s1, nullptr, Vth, Vtl);
    diff_gemm<<<dim3(64, 8), 512, 0, stream>>>(Ahh, All, Vth, Vtl, d2);
    // L1 gate
    StepPtrs P1g{s0, s1, zr, x, Ax, d2, d2, d3};
    gemm_node<2, 128, 256><<<kN, 256, 0, stream>>>(P1g, Wg1, Bg1, zr, nullptr, nullptr, nullptr, t);
    // G3 = A @ (z1*s1) -> dx
    prep_split<<<dim3(16, kB, 1), 256, 0, stream>>>(s1, nullptr, zr, Vth, Vtl);
    diff_gemm<<<dim3(32, 8), 512, 0, stream>>>(Ahh, All, Vth, Vtl, dx);
    // L1 update: s1 <- h1; seq out; lasts[1] at t==T-1
    StepPtrs P1u{s0, s1, zr, x, Ax, d2, d2, dx};
    gemm_node<3, 64, 256><<<kN, 256, 0, stream>>>(P1u, Wu1, Bu1, nullptr, s1, out,
                                                  out + OUT0 + BNH, t);
  }
}

// Round 5
// 4325.057 us; speedup vs baseline: 3.7404x; 1.2996x over previous
//
#include <hip/hip_runtime.h>
#include <cmath>

constexpr int kN = 1024;
constexpr int kB = 64;
constexpr int kT = 12;
constexpr int kH = 64;
constexpr int kE = 16;
constexpr long long OUT0 = (long long)kB * kT * kN * kH;  // 50331648
constexpr long long BNH = (long long)kB * kN * kH;        // 4194304

typedef __attribute__((ext_vector_type(8))) __bf16 bf16x8;
typedef __attribute__((ext_vector_type(4))) float f32x4;

struct StepPtrs {
  const float* s0;
  const float* s1;
  const float* zr;
  const float* x;
  const float* ax;
  const float* d1;
  const float* d2;
  const float* d3;
};

__device__ __forceinline__ float sig_(float v) { return 1.f / (1.f + expf(-v)); }

__device__ __forceinline__ unsigned short f2bf(float f) {
  unsigned u = __float_as_uint(f);
  unsigned r = u + 0x7FFFu + ((u >> 16) & 1u);
  return (unsigned short)(r >> 16);
}
__device__ __forceinline__ float bf2f(unsigned short s) {
  return __uint_as_float(((unsigned)s) << 16);
}

__device__ __forceinline__ void gload16(const void* g, void* l) {
  __builtin_amdgcn_global_load_lds((const __attribute__((address_space(1))) void*)g,
                                   (__attribute__((address_space(3))) void*)l, 16, 0, 0);
}

// ---- A = softmax(relu(E E^T), axis=1) -> row-major hi/lo bf16 split --------
__global__ void __launch_bounds__(256) compute_A(const float* __restrict__ E,
                                                 unsigned short* __restrict__ Ah,
                                                 unsigned short* __restrict__ Al) {
  int n = blockIdx.x, tx = threadIdx.x;
  __shared__ float En[kE];
  __shared__ float red[4];
  if (tx < kE) En[tx] = E[n * kE + tx];
  __syncthreads();
  float v[4];
  float mx = 0.f;
#pragma unroll
  for (int i = 0; i < 4; ++i) {
    int m = tx + i * 256;
    float s = 0.f;
#pragma unroll
    for (int d = 0; d < kE; ++d) s += En[d] * E[m * kE + d];
    s = fmaxf(s, 0.f);
    v[i] = s;
    mx = fmaxf(mx, s);
  }
#pragma unroll
  for (int off = 32; off; off >>= 1) mx = fmaxf(mx, __shfl_down(mx, off));
  int wid = tx >> 6, lane = tx & 63;
  if (lane == 0) red[wid] = mx;
  __syncthreads();
  mx = fmaxf(fmaxf(red[0], red[1]), fmaxf(red[2], red[3]));
  __syncthreads();
  float sum = 0.f;
#pragma unroll
  for (int i = 0; i < 4; ++i) {
    v[i] = expf(v[i] - mx);
    sum += v[i];
  }
#pragma unroll
  for (int off = 32; off; off >>= 1) sum += __shfl_down(sum, off);
  if (lane == 0) red[wid] = sum;
  __syncthreads();
  sum = red[0] + red[1] + red[2] + red[3];
  float inv = 1.f / sum;
#pragma unroll
  for (int i = 0; i < 4; ++i) {
    int m = tx + i * 256;
    float a = v[i] * inv;
    unsigned short h = f2bf(a);
    Ah[n * kN + m] = h;
    Al[n * kN + m] = f2bf(a - bf2f(h));
  }
}

// ---- per-node weights, TRANSPOSED + PADDED hi/lo bf16 ----------------------
// out Wh/Wl[((n*O + o)*KIp + ki], ki >= KI -> 0.
// mode 0 (L1, KI=256, Idim=128): ki<128 -> k=0,i=ki ; else k=1,i=ki-128
// mode 1 (L0, KI=132, Idim=66):  ki<128 -> k=ki>>6,i=(ki&63)+2 ;
//                                128..131 -> k=(ki-128)>>1, i=(ki-128)&1
__global__ void __launch_bounds__(256) mkw2(const float* __restrict__ E,
                                            const float* __restrict__ Wsrc,
                                            unsigned short* __restrict__ Wh,
                                            unsigned short* __restrict__ Wl,
                                            int O, int KI, int KIp, int Idim, int mode) {
  int o = blockIdx.x;
  int n0 = blockIdx.y * 128;
  int ki = threadIdx.x;
  __shared__ float Es[128][kE + 1];
  for (int idx = threadIdx.x; idx < 128 * kE; idx += 256)
    Es[idx >> 4][idx & 15] = E[(n0 + (idx >> 4)) * kE + (idx & 15)];
  __syncthreads();
  if (ki >= KIp) return;
  float w[kE];
  if (ki < KI) {
    int k, i;
    if (mode == 0) {
      k = ki >> 7;
      i = ki & 127;
    } else {
      if (ki < 128) {
        k = ki >> 6;
        i = (ki & 63) + 2;
      } else {
        k = (ki - 128) >> 1;
        i = (ki - 128) & 1;
      }
    }
#pragma unroll
    for (int d = 0; d < kE; ++d) w[d] = Wsrc[((d * 2 + k) * Idim + i) * O + o];
  } else {
#pragma unroll
    for (int d = 0; d < kE; ++d) w[d] = 0.f;
  }
  for (int nn = 0; nn < 128; ++nn) {
    float acc = 0.f;
#pragma unroll
    for (int d = 0; d < kE; ++d) acc += Es[nn][d] * w[d];
    unsigned short h = f2bf(acc);
    long long oidx = ((long long)(n0 + nn) * O + o) * KIp + ki;
    Wh[oidx] = h;
    Wl[oidx] = f2bf(acc - bf2f(h));
  }
}

// ---- per-node biases (fp32): out[n][o] = sum_d E[n,d] b[d][o] --------------
__global__ void __launch_bounds__(256) mkb(const float* __restrict__ E,
                                           const float* __restrict__ bsrc,
                                           float* __restrict__ out, int O) {
  int o = blockIdx.x * 256 + threadIdx.x;
  if (o >= O) return;
  float w[kE];
#pragma unroll
  for (int d = 0; d < kE; ++d) w[d] = bsrc[d * O + o];
  for (int n = 0; n < kN; ++n) {
    float acc = 0.f;
#pragma unroll
    for (int d = 0; d < kE; ++d) acc += E[n * kE + d] * w[d];
    out[n * O + o] = acc;
  }
}

// ---- prep x: x[bt,m,c(2)] -> Xt hi/lo [col=bt*2+c][m] ----------------------
__global__ void __launch_bounds__(256) prep_x(const float* __restrict__ x,
                                              unsigned short* __restrict__ Vth,
                                              unsigned short* __restrict__ Vtl) {
  int m0 = blockIdx.x * 64, bt0 = blockIdx.y * 32, tid = threadIdx.x;
  __shared__ float T[64][65];
  for (int idx = tid; idx < 2048; idx += 256) {
    int mi = idx & 63, j = idx >> 6;
    float2 v = *(const float2*)&x[((long long)(bt0 + j) * kN + m0 + mi) * 2];
    T[j * 2 + 0][mi] = v.x;
    T[j * 2 + 1][mi] = v.y;
  }
  __syncthreads();
  for (int idx = tid; idx < 1024; idx += 256) {
    int cc = idx >> 4, mi4 = (idx & 15) * 4;
    float4 v = *(const float4*)&T[cc][mi4];
    ushort4 h, l;
    h.x = f2bf(v.x); l.x = f2bf(v.x - bf2f(h.x));
    h.y = f2bf(v.y); l.y = f2bf(v.y - bf2f(h.y));
    h.z = f2bf(v.z); l.z = f2bf(v.z - bf2f(h.z));
    h.w = f2bf(v.w); l.w = f2bf(v.w - bf2f(h.w));
    long long o = (long long)(bt0 * 2 + cc) * kN + m0 + mi4;
    *(ushort4*)&Vth[o] = h;
    *(ushort4*)&Vtl[o] = l;
  }
}

// ---- prep: V[b,m,c] (opt *mul) -> transposed hi/lo bf16 --------------------
__global__ void __launch_bounds__(256) prep_split(const float* __restrict__ srcA,
                                                  const float* __restrict__ srcB,
                                                  const float* __restrict__ mul,
                                                  unsigned short* __restrict__ Vth,
                                                  unsigned short* __restrict__ Vtl) {
  int b = blockIdx.y, m0 = blockIdx.x * 64, tid = threadIdx.x;
  int z = blockIdx.z;
  const float* src = z ? srcB : srcA;
  int colBase = z * 4096;
  __shared__ float T[64][65];
  for (int idx = tid; idx < 1024; idx += 256) {
    int mi = idx >> 4, c4 = (idx & 15) * 4;
    long long rowi = (long long)b * kN + m0 + mi;
    float4 v = *(const float4*)&src[rowi * 64 + c4];
    if (mul) {
      float4 mz = *(const float4*)&mul[rowi * 128 + c4];
      v.x *= mz.x; v.y *= mz.y; v.z *= mz.z; v.w *= mz.w;
    }
    T[c4 + 0][mi] = v.x;
    T[c4 + 1][mi] = v.y;
    T[c4 + 2][mi] = v.z;
    T[c4 + 3][mi] = v.w;
  }
  __syncthreads();
  for (int idx = tid; idx < 1024; idx += 256) {
    int c = idx >> 4, mi4 = (idx & 15) * 4;
    float4 v = *(const float4*)&T[c][mi4];
    ushort4 h, l;
    h.x = f2bf(v.x); l.x = f2bf(v.x - bf2f(h.x));
    h.y = f2bf(v.y); l.y = f2bf(v.y - bf2f(h.y));
    h.z = f2bf(v.z); l.z = f2bf(v.z - bf2f(h.z));
    h.w = f2bf(v.w); l.w = f2bf(v.w - bf2f(h.w));
    long long o = (long long)(colBase + b * 64 + c) * kN + m0 + mi4;
    *(ushort4*)&Vth[o] = h;
    *(ushort4*)&Vtl[o] = l;
  }
}

// ---- diffusion GEMM (2-phase double-buffered) -------------------------------
// out[((col>>sh)*kN + n) << sh | (col & (2^sh-1))] = sum_m A[n,m] V[m,col]
__global__ void __launch_bounds__(512, 4) diff_gemm(const unsigned short* __restrict__ Ah,
                                                    const unsigned short* __restrict__ Al,
                                                    const unsigned short* __restrict__ Vth,
                                                    const unsigned short* __restrict__ Vtl,
                                                    float* __restrict__ outp, int sh) {
  __shared__ __align__(16) unsigned short lds[2][16384];
  int tid = threadIdx.x;
  int lane = tid & 63;
  int q = lane >> 4, r16 = lane & 15;
  int wave = tid >> 6;
  int wm = wave >> 2, wn = wave & 3;
  int m0 = blockIdx.y * 128, n0 = blockIdx.x * 128;

  const unsigned short* gsrc[4];
  int ldst[4];
#pragma unroll
  for (int j = 0; j < 4; ++j) {
    int ci = j * 512 + tid;
    int tile = ci >> 9, idx = ci & 511;
    int row = idx >> 2, sp = idx & 3;
    int sl = sp ^ ((row >> 1) & 3);
    const unsigned short* s = (tile == 0) ? Ah : (tile == 1) ? Al : (tile == 2) ? Vth : Vtl;
    int gr = ((tile < 2) ? m0 : n0) + row;
    gsrc[j] = s + (long long)gr * kN + sl * 8;
    ldst[j] = ci * 8;
  }
  int aoff[4][2], voff[2][2];
#pragma unroll
  for (int fm = 0; fm < 4; ++fm) {
    int row = wm * 64 + fm * 16 + r16;
    int s = (q ^ ((row >> 1) & 3)) * 8;
    aoff[fm][0] = row * 32 + s;
    aoff[fm][1] = 4096 + row * 32 + s;
  }
#pragma unroll
  for (int fn = 0; fn < 2; ++fn) {
    int col = wn * 32 + fn * 16 + r16;
    int s = (q ^ ((col >> 1) & 3)) * 8;
    voff[fn][0] = 8192 + col * 32 + s;
    voff[fn][1] = 12288 + col * 32 + s;
  }
  f32x4 acc[4][2];
#pragma unroll
  for (int fm = 0; fm < 4; ++fm)
#pragma unroll
    for (int fn = 0; fn < 2; ++fn) acc[fm][fn] = (f32x4){0.f, 0.f, 0.f, 0.f};

  auto STAGE = [&](int buf, int kt) {
#pragma unroll
    for (int j = 0; j < 4; ++j) gload16(gsrc[j] + kt * 32, &lds[buf][ldst[j]]);
  };
  auto COMPUTE = [&](int buf) {
    const unsigned short* L = &lds[buf][0];
    bf16x8 ah[4], al[4], vh[2], vl[2];
#pragma unroll
    for (int fm = 0; fm < 4; ++fm) {
      ah[fm] = *(const bf16x8*)&L[aoff[fm][0]];
      al[fm] = *(const bf16x8*)&L[aoff[fm][1]];
    }
#pragma unroll
    for (int fn = 0; fn < 2; ++fn) {
      vh[fn] = *(const bf16x8*)&L[voff[fn][0]];
      vl[fn] = *(const bf16x8*)&L[voff[fn][1]];
    }
#pragma unroll
    for (int fm = 0; fm < 4; ++fm)
#pragma unroll
      for (int fn = 0; fn < 2; ++fn) {
        acc[fm][fn] =
            __builtin_amdgcn_mfma_f32_16x16x32_bf16(ah[fm], vh[fn], acc[fm][fn], 0, 0, 0);
        acc[fm][fn] =
            __builtin_amdgcn_mfma_f32_16x16x32_bf16(ah[fm], vl[fn], acc[fm][fn], 0, 0, 0);
        acc[fm][fn] =
            __builtin_amdgcn_mfma_f32_16x16x32_bf16(al[fm], vh[fn], acc[fm][fn], 0, 0, 0);
      }
  };

  STAGE(0, 0);
  asm volatile("s_waitcnt vmcnt(0)" ::: "memory");
  __builtin_amdgcn_s_barrier();
#pragma unroll 1
  for (int kt = 0; kt < 30; kt += 2) {
    STAGE(1, kt + 1);
    COMPUTE(0);
    asm volatile("s_waitcnt vmcnt(0)" ::: "memory");
    __builtin_amdgcn_s_barrier();
    STAGE(0, kt + 2);
    COMPUTE(1);
    asm volatile("s_waitcnt vmcnt(0)" ::: "memory");
    __builtin_amdgcn_s_barrier();
  }
  STAGE(1, 31);
  COMPUTE(0);
  asm volatile("s_waitcnt vmcnt(0)" ::: "memory");
  __builtin_amdgcn_s_barrier();
  COMPUTE(1);

  int msk = (1 << sh) - 1;
#pragma unroll
  for (int fm = 0; fm < 4; ++fm)
#pragma unroll
    for (int fn = 0; fn < 2; ++fn) {
      int nrow = m0 + wm * 64 + fm * 16 + q * 4;
      int col = n0 + wn * 32 + fn * 16 + r16;
      long long b = col >> sh;
      int c = col & msk;
#pragma unroll
      for (int r = 0; r < 4; ++r)
        outp[(((b * kN + nrow + r)) << sh) + c] = acc[fm][fn][r];
    }
}

// ---- per-node MFMA GEMM + fused gate epilogue -------------------------------
// block = node n, 4 waves. C[64b x O] = X[64b x KIp] @ Wn[KIp x O], split-bf16.
// X gathered into LDS once (stride-padded); W b128 frags read from global.
template <int VAR, int O, int KIp>
__global__ void __launch_bounds__(256, 2) mfma_node(StepPtrs P,
                                                    const unsigned short* __restrict__ Wh,
                                                    const unsigned short* __restrict__ Wl,
                                                    const float* __restrict__ bias,
                                                    float* __restrict__ zr_out,
                                                    float* __restrict__ state_out,
                                                    float* __restrict__ seq_out,
                                                    float* __restrict__ last_out, int t) {
  constexpr int S = KIp + 8;  // LDS row stride (elements)
  constexpr int NKT = KIp / 32;
  constexpr int NF = (O == 128) ? 2 : 1;
  __shared__ __align__(16) unsigned short Xh[64 * S];
  __shared__ __align__(16) unsigned short Xl[64 * S];
  int n = blockIdx.x;
  int tid = threadIdx.x;

  auto put4 = [&](int b, int c, float4 v) {
    ushort4 h, l;
    h.x = f2bf(v.x); l.x = f2bf(v.x - bf2f(h.x));
    h.y = f2bf(v.y); l.y = f2bf(v.y - bf2f(h.y));
    h.z = f2bf(v.z); l.z = f2bf(v.z - bf2f(h.z));
    h.w = f2bf(v.w); l.w = f2bf(v.w - bf2f(h.w));
    *(ushort4*)&Xh[b * S + c] = h;
    *(ushort4*)&Xl[b * S + c] = l;
  };

  if constexpr (VAR == 0 || VAR == 1) {
    // X = [s0(*z) | d1 | x_t(2) | ax(2) | pad..160)
    for (int idx = tid; idx < 1024; idx += 256) {
      int b = idx >> 4, c4 = (idx & 15) << 2;
      long long bn = (long long)b * kN + n;
      float4 v0 = *(const float4*)&P.s0[bn * 64 + c4];
      if (VAR == 1) {
        float4 z = *(const float4*)&P.zr[bn * 128 + c4];
        v0.x *= z.x; v0.y *= z.y; v0.z *= z.z; v0.w *= z.w;
      }
      put4(b, c4, v0);
      float4 v1 = *(const float4*)&P.d1[bn * 64 + c4];
      put4(b, 64 + c4, v1);
    }
    if (tid < 128) {
      int b = tid >> 1, c = tid & 1;
      long long btn = ((long long)b * kT + t) * kN + n;
      float vx = P.x[btn * 2 + c];
      float va = P.ax[btn * 2 + c];
      unsigned short h = f2bf(vx);
      Xh[b * S + 128 + c] = h;
      Xl[b * S + 128 + c] = f2bf(vx - bf2f(h));
      h = f2bf(va);
      Xh[b * S + 130 + c] = h;
      Xl[b * S + 130 + c] = f2bf(va - bf2f(h));
    }
    for (int idx = tid; idx < 448; idx += 256) {  // zero pad ki 132..159
      int b = idx / 7, c = 132 + (idx % 7) * 4;
      ushort4 zz = {0, 0, 0, 0};
      *(ushort4*)&Xh[b * S + c] = zz;
      *(ushort4*)&Xl[b * S + c] = zz;
    }
  } else {
    // X = [s0 | s1(*z) | d2 | d3]  (256)
    for (int idx = tid; idx < 1024; idx += 256) {
      int b = idx >> 4, c4 = (idx & 15) << 2;
      long long bn = (long long)b * kN + n;
      float4 v0 = *(const float4*)&P.s0[bn * 64 + c4];
      put4(b, c4, v0);
      float4 v1 = *(const float4*)&P.s1[bn * 64 + c4];
      if (VAR == 3) {
        float4 z = *(const float4*)&P.zr[bn * 128 + c4];
        v1.x *= z.x; v1.y *= z.y; v1.z *= z.z; v1.w *= z.w;
      }
      put4(b, 64 + c4, v1);
      float4 v2 = *(const float4*)&P.d2[bn * 64 + c4];
      put4(b, 128 + c4, v2);
      float4 v3 = *(const float4*)&P.d3[bn * 64 + c4];
      put4(b, 192 + c4, v3);
    }
  }
  __syncthreads();

  int lane = tid & 63, wave = tid >> 6;
  int q = lane >> 4, r16 = lane & 15;
  int colbase = (O == 128) ? wave * 32 : wave * 16;
  f32x4 acc[4][NF];
#pragma unroll
  for (int fm = 0; fm < 4; ++fm)
#pragma unroll
    for (int fn = 0; fn < NF; ++fn) acc[fm][fn] = (f32x4){0.f, 0.f, 0.f, 0.f};

#pragma unroll 2
  for (int kt = 0; kt < NKT; ++kt) {
    int kb = kt * 32 + q * 8;
    bf16x8 xh[4], xl[4], wh[NF], wl[NF];
#pragma unroll
    for (int fm = 0; fm < 4; ++fm) {
      xh[fm] = *(const bf16x8*)&Xh[(fm * 16 + r16) * S + kb];
      xl[fm] = *(const bf16x8*)&Xl[(fm * 16 + r16) * S + kb];
    }
#pragma unroll
    for (int fn = 0; fn < NF; ++fn) {
      int o = colbase + fn * 16 + r16;
      long long wo = ((long long)n * O + o) * KIp + kb;
      wh[fn] = *(const bf16x8*)&Wh[wo];
      wl[fn] = *(const bf16x8*)&Wl[wo];
    }
#pragma unroll
    for (int fm = 0; fm < 4; ++fm)
#pragma unroll
      for (int fn = 0; fn < NF; ++fn) {
        acc[fm][fn] =
            __builtin_amdgcn_mfma_f32_16x16x32_bf16(xh[fm], wh[fn], acc[fm][fn], 0, 0, 0);
        acc[fm][fn] =
            __builtin_amdgcn_mfma_f32_16x16x32_bf16(xh[fm], wl[fn], acc[fm][fn], 0, 0, 0);
        acc[fm][fn] =
            __builtin_amdgcn_mfma_f32_16x16x32_bf16(xl[fm], wh[fn], acc[fm][fn], 0, 0, 0);
      }
  }

  if constexpr (O == 128) {  // gate: zr = sigmoid(acc + bias)
#pragma unroll
    for (int fn = 0; fn < NF; ++fn) {
      int o = colbase + fn * 16 + r16;
      float bb = bias[n * 128 + o];
#pragma unroll
      for (int fm = 0; fm < 4; ++fm) {
#pragma unroll
        for (int r = 0; r < 4; ++r) {
          int b = fm * 16 + q * 4 + r;
          zr_out[((long long)b * kN + n) * 128 + o] = sig_(acc[fm][fn][r] + bb);
        }
      }
    }
  } else {  // update: h = r*s + (1-r)*tanh(acc + bias)
    const float* sptr = (VAR == 1) ? P.s0 : P.s1;
    int o = colbase + r16;
    float bb = bias[n * 64 + o];
#pragma unroll
    for (int fm = 0; fm < 4; ++fm) {
#pragma unroll
      for (int r = 0; r < 4; ++r) {
        int b = fm * 16 + q * 4 + r;
        long long bn = (long long)b * kN + n;
        float rr = P.zr[bn * 128 + 64 + o];
        float ss = sptr[bn * 64 + o];
        float h = rr * ss + (1.f - rr) * tanhf(acc[fm][0][r] + bb);
        state_out[bn * 64 + o] = h;
        if constexpr (VAR == 3) {
          seq_out[(((long long)b * kT + t) * kN + n) * 64 + o] = h;
        }
        if (t == kT - 1) last_out[bn * 64 + o] = h;
      }
    }
  }
}

extern "C" void kernel_launch(void* const* d_in, const int* in_sizes, int n_in, void* d_out,
                              int out_size, void* d_ws, size_t ws_size, hipStream_t stream) {
  (void)in_sizes; (void)n_in; (void)out_size; (void)ws_size;
  const float* x   = (const float*)d_in[0];
  const float* ist = (const float*)d_in[1];
  const float* E   = (const float*)d_in[2];
  const float* gw0 = (const float*)d_in[3];
  const float* gb0 = (const float*)d_in[4];
  const float* uw0 = (const float*)d_in[5];
  const float* ub0 = (const float*)d_in[6];
  const float* gw1 = (const float*)d_in[7];
  const float* gb1 = (const float*)d_in[8];
  const float* uw1 = (const float*)d_in[9];
  const float* ub1 = (const float*)d_in[10];
  float* out = (float*)d_out;

  char* base = (char*)d_ws;
  size_t off = 0;
  auto alloc = [&](size_t bytes) {
    char* p = base + off;
    off += (bytes + 1023) & ~(size_t)1023;
    return p;
  };
  unsigned short* Vth = (unsigned short*)alloc((size_t)8192 * kN * 2);
  unsigned short* Vtl = (unsigned short*)alloc((size_t)8192 * kN * 2);
  unsigned short* Ahh = (unsigned short*)alloc((size_t)kN * kN * 2);
  unsigned short* All = (unsigned short*)alloc((size_t)kN * kN * 2);
  float* Ax = (float*)alloc((size_t)kB * kT * kN * 2 * 4);
  unsigned short* Wg0h = (unsigned short*)alloc((size_t)kN * 128 * 160 * 2);
  unsigned short* Wg0l = (unsigned short*)alloc((size_t)kN * 128 * 160 * 2);
  unsigned short* Wu0h = (unsigned short*)alloc((size_t)kN * 64 * 160 * 2);
  unsigned short* Wu0l = (unsigned short*)alloc((size_t)kN * 64 * 160 * 2);
  unsigned short* Wg1h = (unsigned short*)alloc((size_t)kN * 128 * 256 * 2);
  unsigned short* Wg1l = (unsigned short*)alloc((size_t)kN * 128 * 256 * 2);
  unsigned short* Wu1h = (unsigned short*)alloc((size_t)kN * 64 * 256 * 2);
  unsigned short* Wu1l = (unsigned short*)alloc((size_t)kN * 64 * 256 * 2);
  float* Bg0 = (float*)alloc((size_t)kN * 128 * 4);
  float* Bu0 = (float*)alloc((size_t)kN * 64 * 4);
  float* Bg1 = (float*)alloc((size_t)kN * 128 * 4);
  float* Bu1 = (float*)alloc((size_t)kN * 64 * 4);
  float* s0 = (float*)alloc((size_t)BNH * 4);
  float* s1 = (float*)alloc((size_t)BNH * 4);
  float* dx = (float*)alloc((size_t)BNH * 4);
  float* dd = (float*)alloc((size_t)BNH * 2 * 4);  // [d2 | d3]
  float* zr = (float*)alloc((size_t)kB * kN * 128 * 4);
  float* d2 = dd;
  float* d3 = dd + BNH;

  const size_t stateBytes = (size_t)BNH * sizeof(float);
  (void)hipMemcpyAsync(s0, ist, stateBytes, hipMemcpyDeviceToDevice, stream);
  (void)hipMemcpyAsync(s1, ist + BNH, stateBytes, hipMemcpyDeviceToDevice, stream);

  compute_A<<<kN, 256, 0, stream>>>(E, Ahh, All);
  // x diffusion through the MFMA path: Ax[bt,n,c] = sum_m A[n,m] x[bt,m,c]
  prep_x<<<dim3(16, 24), 256, 0, stream>>>(x, Vth, Vtl);
  diff_gemm<<<dim3(12, 8), 512, 0, stream>>>(Ahh, All, Vth, Vtl, Ax, 1);

  mkw2<<<dim3(128, 8), 256, 0, stream>>>(E, gw0, Wg0h, Wg0l, 128, 132, 160, 66, 1);
  mkw2<<<dim3(64, 8), 256, 0, stream>>>(E, uw0, Wu0h, Wu0l, 64, 132, 160, 66, 1);
  mkw2<<<dim3(128, 8), 256, 0, stream>>>(E, gw1, Wg1h, Wg1l, 128, 256, 256, 128, 0);
  mkw2<<<dim3(64, 8), 256, 0, stream>>>(E, uw1, Wu1h, Wu1l, 64, 256, 256, 128, 0);
  mkb<<<1, 256, 0, stream>>>(E, gb0, Bg0, 128);
  mkb<<<1, 256, 0, stream>>>(E, ub0, Bu0, 64);
  mkb<<<1, 256, 0, stream>>>(E, gb1, Bg1, 128);
  mkb<<<1, 256, 0, stream>>>(E, ub1, Bu1, 64);

  // bootstrap: d2 = A @ s0_init
  prep_split<<<dim3(16, kB, 1), 256, 0, stream>>>(s0, nullptr, nullptr, Vth, Vtl);
  diff_gemm<<<dim3(32, 8), 512, 0, stream>>>(Ahh, All, Vth, Vtl, d2, 6);

  for (int t = 0; t < kT; ++t) {
    // L0 gate (diffused state = d2 from previous step / bootstrap)
    StepPtrs Pg0{s0, s1, zr, x, Ax, d2, d2, d3};
    mfma_node<0, 128, 160><<<kN, 256, 0, stream>>>(Pg0, Wg0h, Wg0l, Bg0, zr, nullptr,
                                                   nullptr, nullptr, t);
    // G1 = A @ (z0*s0) -> dx
    prep_split<<<dim3(16, kB, 1), 256, 0, stream>>>(s0, nullptr, zr, Vth, Vtl);
    diff_gemm<<<dim3(32, 8), 512, 0, stream>>>(Ahh, All, Vth, Vtl, dx, 6);
    // L0 update: s0 <- h0; lasts[0] at t==T-1
    StepPtrs Pu0{s0, s1, zr, x, Ax, dx, d2, d3};
    mfma_node<1, 64, 160><<<kN, 256, 0, stream>>>(Pu0, Wu0h, Wu0l, Bu0, nullptr, s0,
                                                  nullptr, out + OUT0, t);
    // G2 = A @ [h0 ; s1] -> [d2 | d3]
    prep_split<<<dim3(16, kB, 2), 256, 0, stream>>>(s0, s1, nullptr, Vth, Vtl);
    diff_gemm<<<dim3(64, 8), 512, 0, stream>>>(Ahh, All, Vth, Vtl, d2, 6);
    // L1 gate
    StepPtrs P1g{s0, s1, zr, x, Ax, d2, d2, d3};
    mfma_node<2, 128, 256><<<kN, 256, 0, stream>>>(P1g, Wg1h, Wg1l, Bg1, zr, nullptr,
                                                   nullptr, nullptr, t);
    // G3 = A @ (z1*s1) -> dx
    prep_split<<<dim3(16, kB, 1), 256, 0, stream>>>(s1, nullptr, zr, Vth, Vtl);
    diff_gemm<<<dim3(32, 8), 512, 0, stream>>>(Ahh, All, Vth, Vtl, dx, 6);
    // L1 update: s1 <- h1; seq out; lasts[1] at t==T-1
    StepPtrs P1u{s0, s1, zr, x, Ax, d2, d2, dx};
    mfma_node<3, 64, 256><<<kN, 256, 0, stream>>>(P1u, Wu1h, Wu1l, Bu1, nullptr, s1, out,
                                                  out + OUT0 + BNH, t);
  }
}

// Round 6
// 3866.143 us; speedup vs baseline: 4.1844x; 1.1187x over previous
//
#include <hip/hip_runtime.h>
#include <cmath>

constexpr int kN = 1024;
constexpr int kB = 64;
constexpr int kT = 12;
constexpr int kH = 64;
constexpr int kE = 16;
constexpr long long OUT0 = (long long)kB * kT * kN * kH;  // 50331648
constexpr long long BNH = (long long)kB * kN * kH;        // 4194304

typedef __attribute__((ext_vector_type(8))) __bf16 bf16x8;
typedef __attribute__((ext_vector_type(4))) float f32x4;

struct StepPtrs {
  const float* s0;
  const float* s1;
  const float* zr;
  const float* x;
  const float* ax;
  const float* d1;
  const float* d2;
  const float* d3;
};

__device__ __forceinline__ float sig_(float v) { return 1.f / (1.f + expf(-v)); }

__device__ __forceinline__ unsigned short f2bf(float f) {
  unsigned u = __float_as_uint(f);
  unsigned r = u + 0x7FFFu + ((u >> 16) & 1u);
  return (unsigned short)(r >> 16);
}
__device__ __forceinline__ float bf2f(unsigned short s) {
  return __uint_as_float(((unsigned)s) << 16);
}

__device__ __forceinline__ void gload16(const void* g, void* l) {
  __builtin_amdgcn_global_load_lds((const __attribute__((address_space(1))) void*)g,
                                   (__attribute__((address_space(3))) void*)l, 16, 0, 0);
}

// ---- A = softmax(relu(E E^T), axis=1) -> row-major hi/lo bf16 split --------
__global__ void __launch_bounds__(256) compute_A(const float* __restrict__ E,
                                                 unsigned short* __restrict__ Ah,
                                                 unsigned short* __restrict__ Al) {
  int n = blockIdx.x, tx = threadIdx.x;
  __shared__ float En[kE];
  __shared__ float red[4];
  if (tx < kE) En[tx] = E[n * kE + tx];
  __syncthreads();
  float v[4];
  float mx = 0.f;
#pragma unroll
  for (int i = 0; i < 4; ++i) {
    int m = tx + i * 256;
    float s = 0.f;
#pragma unroll
    for (int d = 0; d < kE; ++d) s += En[d] * E[m * kE + d];
    s = fmaxf(s, 0.f);
    v[i] = s;
    mx = fmaxf(mx, s);
  }
#pragma unroll
  for (int off = 32; off; off >>= 1) mx = fmaxf(mx, __shfl_down(mx, off));
  int wid = tx >> 6, lane = tx & 63;
  if (lane == 0) red[wid] = mx;
  __syncthreads();
  mx = fmaxf(fmaxf(red[0], red[1]), fmaxf(red[2], red[3]));
  __syncthreads();
  float sum = 0.f;
#pragma unroll
  for (int i = 0; i < 4; ++i) {
    v[i] = expf(v[i] - mx);
    sum += v[i];
  }
#pragma unroll
  for (int off = 32; off; off >>= 1) sum += __shfl_down(sum, off);
  if (lane == 0) red[wid] = sum;
  __syncthreads();
  sum = red[0] + red[1] + red[2] + red[3];
  float inv = 1.f / sum;
#pragma unroll
  for (int i = 0; i < 4; ++i) {
    int m = tx + i * 256;
    float a = v[i] * inv;
    unsigned short h = f2bf(a);
    Ah[n * kN + m] = h;
    Al[n * kN + m] = f2bf(a - bf2f(h));
  }
}

// ---- per-node weights, TRANSPOSED + PADDED hi/lo bf16 ----------------------
// out Wh/Wl[((n*O + o)*KIp + ki], ki >= KI -> 0.
// mode 0 (L1, KI=256, Idim=128): ki<128 -> k=0,i=ki ; else k=1,i=ki-128
// mode 1 (L0, KI=132, Idim=66):  ki<128 -> k=ki>>6,i=(ki&63)+2 ;
//                                128..131 -> k=(ki-128)>>1, i=(ki-128)&1
__global__ void __launch_bounds__(256) mkw2(const float* __restrict__ E,
                                            const float* __restrict__ Wsrc,
                                            unsigned short* __restrict__ Wh,
                                            unsigned short* __restrict__ Wl,
                                            int O, int KI, int KIp, int Idim, int mode) {
  int o = blockIdx.x;
  int n0 = blockIdx.y * 128;
  int ki = threadIdx.x;
  __shared__ float Es[128][kE + 1];
  for (int idx = threadIdx.x; idx < 128 * kE; idx += 256)
    Es[idx >> 4][idx & 15] = E[(n0 + (idx >> 4)) * kE + (idx & 15)];
  __syncthreads();
  if (ki >= KIp) return;
  float w[kE];
  if (ki < KI) {
    int k, i;
    if (mode == 0) {
      k = ki >> 7;
      i = ki & 127;
    } else {
      if (ki < 128) {
        k = ki >> 6;
        i = (ki & 63) + 2;
      } else {
        k = (ki - 128) >> 1;
        i = (ki - 128) & 1;
      }
    }
#pragma unroll
    for (int d = 0; d < kE; ++d) w[d] = Wsrc[((d * 2 + k) * Idim + i) * O + o];
  } else {
#pragma unroll
    for (int d = 0; d < kE; ++d) w[d] = 0.f;
  }
  for (int nn = 0; nn < 128; ++nn) {
    float acc = 0.f;
#pragma unroll
    for (int d = 0; d < kE; ++d) acc += Es[nn][d] * w[d];
    unsigned short h = f2bf(acc);
    long long oidx = ((long long)(n0 + nn) * O + o) * KIp + ki;
    Wh[oidx] = h;
    Wl[oidx] = f2bf(acc - bf2f(h));
  }
}

// ---- per-node biases (fp32), parallel over (n,o): grid = kN*O/256 ----------
__global__ void __launch_bounds__(256) mkb(const float* __restrict__ E,
                                           const float* __restrict__ bsrc,
                                           float* __restrict__ out, int O) {
  int idx = blockIdx.x * 256 + threadIdx.x;
  int n = idx / O, o = idx - n * O;
  if (n >= kN) return;
  float acc = 0.f;
#pragma unroll
  for (int d = 0; d < kE; ++d) acc += E[n * kE + d] * bsrc[d * O + o];
  out[idx] = acc;
}

// ---- prep x: x[bt,m,c(2)] -> Xt hi/lo [col=bt*2+c][m] ----------------------
__global__ void __launch_bounds__(256) prep_x(const float* __restrict__ x,
                                              unsigned short* __restrict__ Vth,
                                              unsigned short* __restrict__ Vtl) {
  int m0 = blockIdx.x * 64, bt0 = blockIdx.y * 32, tid = threadIdx.x;
  __shared__ float T[64][65];
  for (int idx = tid; idx < 2048; idx += 256) {
    int mi = idx & 63, j = idx >> 6;
    float2 v = *(const float2*)&x[((long long)(bt0 + j) * kN + m0 + mi) * 2];
    T[j * 2 + 0][mi] = v.x;
    T[j * 2 + 1][mi] = v.y;
  }
  __syncthreads();
  for (int idx = tid; idx < 1024; idx += 256) {
    int cc = idx >> 4, mi4 = (idx & 15) * 4;
    float4 v = *(const float4*)&T[cc][mi4];
    ushort4 h, l;
    h.x = f2bf(v.x); l.x = f2bf(v.x - bf2f(h.x));
    h.y = f2bf(v.y); l.y = f2bf(v.y - bf2f(h.y));
    h.z = f2bf(v.z); l.z = f2bf(v.z - bf2f(h.z));
    h.w = f2bf(v.w); l.w = f2bf(v.w - bf2f(h.w));
    long long o = (long long)(bt0 * 2 + cc) * kN + m0 + mi4;
    *(ushort4*)&Vth[o] = h;
    *(ushort4*)&Vtl[o] = l;
  }
}

// ---- prep: V[b,m,c] (opt *mul) -> transposed hi/lo bf16 --------------------
__global__ void __launch_bounds__(256) prep_split(const float* __restrict__ srcA,
                                                  const float* __restrict__ srcB,
                                                  const float* __restrict__ mul,
                                                  unsigned short* __restrict__ Vth,
                                                  unsigned short* __restrict__ Vtl) {
  int b = blockIdx.y, m0 = blockIdx.x * 64, tid = threadIdx.x;
  int z = blockIdx.z;
  const float* src = z ? srcB : srcA;
  int colBase = z * 4096;
  __shared__ float T[64][65];
  for (int idx = tid; idx < 1024; idx += 256) {
    int mi = idx >> 4, c4 = (idx & 15) * 4;
    long long rowi = (long long)b * kN + m0 + mi;
    float4 v = *(const float4*)&src[rowi * 64 + c4];
    if (mul) {
      float4 mz = *(const float4*)&mul[rowi * 128 + c4];
      v.x *= mz.x; v.y *= mz.y; v.z *= mz.z; v.w *= mz.w;
    }
    T[c4 + 0][mi] = v.x;
    T[c4 + 1][mi] = v.y;
    T[c4 + 2][mi] = v.z;
    T[c4 + 3][mi] = v.w;
  }
  __syncthreads();
  for (int idx = tid; idx < 1024; idx += 256) {
    int c = idx >> 4, mi4 = (idx & 15) * 4;
    float4 v = *(const float4*)&T[c][mi4];
    ushort4 h, l;
    h.x = f2bf(v.x); l.x = f2bf(v.x - bf2f(h.x));
    h.y = f2bf(v.y); l.y = f2bf(v.y - bf2f(h.y));
    h.z = f2bf(v.z); l.z = f2bf(v.z - bf2f(h.z));
    h.w = f2bf(v.w); l.w = f2bf(v.w - bf2f(h.w));
    long long o = (long long)(colBase + b * 64 + c) * kN + m0 + mi4;
    *(ushort4*)&Vth[o] = h;
    *(ushort4*)&Vtl[o] = l;
  }
}

// ---- diffusion GEMM (2-phase double-buffered) -------------------------------
// out[((col>>sh)*kN + n) << sh | (col & (2^sh-1))] = sum_m A[n,m] V[m,col]
__global__ void __launch_bounds__(512, 4) diff_gemm(const unsigned short* __restrict__ Ah,
                                                    const unsigned short* __restrict__ Al,
                                                    const unsigned short* __restrict__ Vth,
                                                    const unsigned short* __restrict__ Vtl,
                                                    float* __restrict__ outp, int sh) {
  __shared__ __align__(16) unsigned short lds[2][16384];
  int tid = threadIdx.x;
  int lane = tid & 63;
  int q = lane >> 4, r16 = lane & 15;
  int wave = tid >> 6;
  int wm = wave >> 2, wn = wave & 3;
  int m0 = blockIdx.y * 128, n0 = blockIdx.x * 128;

  const unsigned short* gsrc[4];
  int ldst[4];
#pragma unroll
  for (int j = 0; j < 4; ++j) {
    int ci = j * 512 + tid;
    int tile = ci >> 9, idx = ci & 511;
    int row = idx >> 2, sp = idx & 3;
    int sl = sp ^ ((row >> 1) & 3);
    const unsigned short* s = (tile == 0) ? Ah : (tile == 1) ? Al : (tile == 2) ? Vth : Vtl;
    int gr = ((tile < 2) ? m0 : n0) + row;
    gsrc[j] = s + (long long)gr * kN + sl * 8;
    ldst[j] = ci * 8;
  }
  int aoff[4][2], voff[2][2];
#pragma unroll
  for (int fm = 0; fm < 4; ++fm) {
    int row = wm * 64 + fm * 16 + r16;
    int s = (q ^ ((row >> 1) & 3)) * 8;
    aoff[fm][0] = row * 32 + s;
    aoff[fm][1] = 4096 + row * 32 + s;
  }
#pragma unroll
  for (int fn = 0; fn < 2; ++fn) {
    int col = wn * 32 + fn * 16 + r16;
    int s = (q ^ ((col >> 1) & 3)) * 8;
    voff[fn][0] = 8192 + col * 32 + s;
    voff[fn][1] = 12288 + col * 32 + s;
  }
  f32x4 acc[4][2];
#pragma unroll
  for (int fm = 0; fm < 4; ++fm)
#pragma unroll
    for (int fn = 0; fn < 2; ++fn) acc[fm][fn] = (f32x4){0.f, 0.f, 0.f, 0.f};

  auto STAGE = [&](int buf, int kt) {
#pragma unroll
    for (int j = 0; j < 4; ++j) gload16(gsrc[j] + kt * 32, &lds[buf][ldst[j]]);
  };
  auto COMPUTE = [&](int buf) {
    const unsigned short* L = &lds[buf][0];
    bf16x8 ah[4], al[4], vh[2], vl[2];
#pragma unroll
    for (int fm = 0; fm < 4; ++fm) {
      ah[fm] = *(const bf16x8*)&L[aoff[fm][0]];
      al[fm] = *(const bf16x8*)&L[aoff[fm][1]];
    }
#pragma unroll
    for (int fn = 0; fn < 2; ++fn) {
      vh[fn] = *(const bf16x8*)&L[voff[fn][0]];
      vl[fn] = *(const bf16x8*)&L[voff[fn][1]];
    }
#pragma unroll
    for (int fm = 0; fm < 4; ++fm)
#pragma unroll
      for (int fn = 0; fn < 2; ++fn) {
        acc[fm][fn] =
            __builtin_amdgcn_mfma_f32_16x16x32_bf16(ah[fm], vh[fn], acc[fm][fn], 0, 0, 0);
        acc[fm][fn] =
            __builtin_amdgcn_mfma_f32_16x16x32_bf16(ah[fm], vl[fn], acc[fm][fn], 0, 0, 0);
        acc[fm][fn] =
            __builtin_amdgcn_mfma_f32_16x16x32_bf16(al[fm], vh[fn], acc[fm][fn], 0, 0, 0);
      }
  };

  STAGE(0, 0);
  asm volatile("s_waitcnt vmcnt(0)" ::: "memory");
  __builtin_amdgcn_s_barrier();
#pragma unroll 1
  for (int kt = 0; kt < 30; kt += 2) {
    STAGE(1, kt + 1);
    COMPUTE(0);
    asm volatile("s_waitcnt vmcnt(0)" ::: "memory");
    __builtin_amdgcn_s_barrier();
    STAGE(0, kt + 2);
    COMPUTE(1);
    asm volatile("s_waitcnt vmcnt(0)" ::: "memory");
    __builtin_amdgcn_s_barrier();
  }
  STAGE(1, 31);
  COMPUTE(0);
  asm volatile("s_waitcnt vmcnt(0)" ::: "memory");
  __builtin_amdgcn_s_barrier();
  COMPUTE(1);

  int msk = (1 << sh) - 1;
#pragma unroll
  for (int fm = 0; fm < 4; ++fm)
#pragma unroll
    for (int fn = 0; fn < 2; ++fn) {
      int nrow = m0 + wm * 64 + fm * 16 + q * 4;
      int col = n0 + wn * 32 + fn * 16 + r16;
      long long b = col >> sh;
      int c = col & msk;
#pragma unroll
      for (int r = 0; r < 4; ++r)
        outp[(((b * kN + nrow + r)) << sh) + c] = acc[fm][fn][r];
    }
}

// ---- per-node MFMA GEMM + fused gate epilogue -------------------------------
// block = node n, 4 waves. C[64b x O] = X[64b x KIp] @ Wn[KIp x O], split-bf16.
// X gathered into LDS once (stride-padded); W b128 frags read from global.
template <int VAR, int O, int KIp>
__global__ void __launch_bounds__(256, 2) mfma_node(StepPtrs P,
                                                    const unsigned short* __restrict__ Wh,
                                                    const unsigned short* __restrict__ Wl,
                                                    const float* __restrict__ bias,
                                                    float* __restrict__ zr_out,
                                                    float* __restrict__ state_out,
                                                    float* __restrict__ seq_out,
                                                    float* __restrict__ last_out, int t) {
  constexpr int S = KIp + 8;  // LDS row stride (elements)
  constexpr int NKT = KIp / 32;
  constexpr int NF = (O == 128) ? 2 : 1;
  __shared__ __align__(16) unsigned short Xh[64 * S];
  __shared__ __align__(16) unsigned short Xl[64 * S];
  int n = blockIdx.x;
  int tid = threadIdx.x;

  auto put4 = [&](int b, int c, float4 v) {
    ushort4 h, l;
    h.x = f2bf(v.x); l.x = f2bf(v.x - bf2f(h.x));
    h.y = f2bf(v.y); l.y = f2bf(v.y - bf2f(h.y));
    h.z = f2bf(v.z); l.z = f2bf(v.z - bf2f(h.z));
    h.w = f2bf(v.w); l.w = f2bf(v.w - bf2f(h.w));
    *(ushort4*)&Xh[b * S + c] = h;
    *(ushort4*)&Xl[b * S + c] = l;
  };

  if constexpr (VAR == 0 || VAR == 1) {
    // X = [s0(*z) | d1 | x_t(2) | ax(2) | pad..160)
    for (int idx = tid; idx < 1024; idx += 256) {
      int b = idx >> 4, c4 = (idx & 15) << 2;
      long long bn = (long long)b * kN + n;
      float4 v0 = *(const float4*)&P.s0[bn * 64 + c4];
      if (VAR == 1) {
        float4 z = *(const float4*)&P.zr[bn * 128 + c4];
        v0.x *= z.x; v0.y *= z.y; v0.z *= z.z; v0.w *= z.w;
      }
      put4(b, c4, v0);
      float4 v1 = *(const float4*)&P.d1[bn * 64 + c4];
      put4(b, 64 + c4, v1);
    }
    if (tid < 128) {
      int b = tid >> 1, c = tid & 1;
      long long btn = ((long long)b * kT + t) * kN + n;
      float vx = P.x[btn * 2 + c];
      float va = P.ax[btn * 2 + c];
      unsigned short h = f2bf(vx);
      Xh[b * S + 128 + c] = h;
      Xl[b * S + 128 + c] = f2bf(vx - bf2f(h));
      h = f2bf(va);
      Xh[b * S + 130 + c] = h;
      Xl[b * S + 130 + c] = f2bf(va - bf2f(h));
    }
    for (int idx = tid; idx < 448; idx += 256) {  // zero pad ki 132..159
      int b = idx / 7, c = 132 + (idx % 7) * 4;
      ushort4 zz = {0, 0, 0, 0};
      *(ushort4*)&Xh[b * S + c] = zz;
      *(ushort4*)&Xl[b * S + c] = zz;
    }
  } else {
    // X = [s0 | s1(*z) | d2 | d3]  (256)
    for (int idx = tid; idx < 1024; idx += 256) {
      int b = idx >> 4, c4 = (idx & 15) << 2;
      long long bn = (long long)b * kN + n;
      float4 v0 = *(const float4*)&P.s0[bn * 64 + c4];
      put4(b, c4, v0);
      float4 v1 = *(const float4*)&P.s1[bn * 64 + c4];
      if (VAR == 3) {
        float4 z = *(const float4*)&P.zr[bn * 128 + c4];
        v1.x *= z.x; v1.y *= z.y; v1.z *= z.z; v1.w *= z.w;
      }
      put4(b, 64 + c4, v1);
      float4 v2 = *(const float4*)&P.d2[bn * 64 + c4];
      put4(b, 128 + c4, v2);
      float4 v3 = *(const float4*)&P.d3[bn * 64 + c4];
      put4(b, 192 + c4, v3);
    }
  }
  __syncthreads();

  int lane = tid & 63, wave = tid >> 6;
  int q = lane >> 4, r16 = lane & 15;
  int colbase = (O == 128) ? wave * 32 : wave * 16;
  f32x4 acc[4][NF];
#pragma unroll
  for (int fm = 0; fm < 4; ++fm)
#pragma unroll
    for (int fn = 0; fn < NF; ++fn) acc[fm][fn] = (f32x4){0.f, 0.f, 0.f, 0.f};

#pragma unroll 2
  for (int kt = 0; kt < NKT; ++kt) {
    int kb = kt * 32 + q * 8;
    bf16x8 xh[4], xl[4], wh[NF], wl[NF];
#pragma unroll
    for (int fm = 0; fm < 4; ++fm) {
      xh[fm] = *(const bf16x8*)&Xh[(fm * 16 + r16) * S + kb];
      xl[fm] = *(const bf16x8*)&Xl[(fm * 16 + r16) * S + kb];
    }
#pragma unroll
    for (int fn = 0; fn < NF; ++fn) {
      int o = colbase + fn * 16 + r16;
      long long wo = ((long long)n * O + o) * KIp + kb;
      wh[fn] = *(const bf16x8*)&Wh[wo];
      wl[fn] = *(const bf16x8*)&Wl[wo];
    }
#pragma unroll
    for (int fm = 0; fm < 4; ++fm)
#pragma unroll
      for (int fn = 0; fn < NF; ++fn) {
        acc[fm][fn] =
            __builtin_amdgcn_mfma_f32_16x16x32_bf16(xh[fm], wh[fn], acc[fm][fn], 0, 0, 0);
        acc[fm][fn] =
            __builtin_amdgcn_mfma_f32_16x16x32_bf16(xh[fm], wl[fn], acc[fm][fn], 0, 0, 0);
        acc[fm][fn] =
            __builtin_amdgcn_mfma_f32_16x16x32_bf16(xl[fm], wh[fn], acc[fm][fn], 0, 0, 0);
      }
  }

  if constexpr (O == 128) {  // gate: zr = sigmoid(acc + bias)
#pragma unroll
    for (int fn = 0; fn < NF; ++fn) {
      int o = colbase + fn * 16 + r16;
      float bb = bias[n * 128 + o];
#pragma unroll
      for (int fm = 0; fm < 4; ++fm) {
#pragma unroll
        for (int r = 0; r < 4; ++r) {
          int b = fm * 16 + q * 4 + r;
          zr_out[((long long)b * kN + n) * 128 + o] = sig_(acc[fm][fn][r] + bb);
        }
      }
    }
  } else {  // update: h = r*s + (1-r)*tanh(acc + bias)
    const float* sptr = (VAR == 1) ? P.s0 : P.s1;
    int o = colbase + r16;
    float bb = bias[n * 64 + o];
#pragma unroll
    for (int fm = 0; fm < 4; ++fm) {
#pragma unroll
      for (int r = 0; r < 4; ++r) {
        int b = fm * 16 + q * 4 + r;
        long long bn = (long long)b * kN + n;
        float rr = P.zr[bn * 128 + 64 + o];
        float ss = sptr[bn * 64 + o];
        float h = rr * ss + (1.f - rr) * tanhf(acc[fm][0][r] + bb);
        state_out[bn * 64 + o] = h;
        if constexpr (VAR == 3) {
          seq_out[(((long long)b * kT + t) * kN + n) * 64 + o] = h;
        }
        if (t == kT - 1) last_out[bn * 64 + o] = h;
      }
    }
  }
}

extern "C" void kernel_launch(void* const* d_in, const int* in_sizes, int n_in, void* d_out,
                              int out_size, void* d_ws, size_t ws_size, hipStream_t stream) {
  (void)in_sizes; (void)n_in; (void)out_size; (void)ws_size;
  const float* x   = (const float*)d_in[0];
  const float* ist = (const float*)d_in[1];
  const float* E   = (const float*)d_in[2];
  const float* gw0 = (const float*)d_in[3];
  const float* gb0 = (const float*)d_in[4];
  const float* uw0 = (const float*)d_in[5];
  const float* ub0 = (const float*)d_in[6];
  const float* gw1 = (const float*)d_in[7];
  const float* gb1 = (const float*)d_in[8];
  const float* uw1 = (const float*)d_in[9];
  const float* ub1 = (const float*)d_in[10];
  float* out = (float*)d_out;

  char* base = (char*)d_ws;
  size_t off = 0;
  auto alloc = [&](size_t bytes) {
    char* p = base + off;
    off += (bytes + 1023) & ~(size_t)1023;
    return p;
  };
  unsigned short* Vth = (unsigned short*)alloc((size_t)8192 * kN * 2);
  unsigned short* Vtl = (unsigned short*)alloc((size_t)8192 * kN * 2);
  unsigned short* Ahh = (unsigned short*)alloc((size_t)kN * kN * 2);
  unsigned short* All = (unsigned short*)alloc((size_t)kN * kN * 2);
  float* Ax = (float*)alloc((size_t)kB * kT * kN * 2 * 4);
  unsigned short* Wg0h = (unsigned short*)alloc((size_t)kN * 128 * 160 * 2);
  unsigned short* Wg0l = (unsigned short*)alloc((size_t)kN * 128 * 160 * 2);
  unsigned short* Wu0h = (unsigned short*)alloc((size_t)kN * 64 * 160 * 2);
  unsigned short* Wu0l = (unsigned short*)alloc((size_t)kN * 64 * 160 * 2);
  unsigned short* Wg1h = (unsigned short*)alloc((size_t)kN * 128 * 256 * 2);
  unsigned short* Wg1l = (unsigned short*)alloc((size_t)kN * 128 * 256 * 2);
  unsigned short* Wu1h = (unsigned short*)alloc((size_t)kN * 64 * 256 * 2);
  unsigned short* Wu1l = (unsigned short*)alloc((size_t)kN * 64 * 256 * 2);
  float* Bg0 = (float*)alloc((size_t)kN * 128 * 4);
  float* Bu0 = (float*)alloc((size_t)kN * 64 * 4);
  float* Bg1 = (float*)alloc((size_t)kN * 128 * 4);
  float* Bu1 = (float*)alloc((size_t)kN * 64 * 4);
  float* s0 = (float*)alloc((size_t)BNH * 4);
  float* s1 = (float*)alloc((size_t)BNH * 4);
  float* dx = (float*)alloc((size_t)BNH * 4);
  float* dd = (float*)alloc((size_t)BNH * 2 * 4);  // [d2 | d3]
  float* zr = (float*)alloc((size_t)kB * kN * 128 * 4);
  float* d2 = dd;
  float* d3 = dd + BNH;

  const size_t stateBytes = (size_t)BNH * sizeof(float);
  (void)hipMemcpyAsync(s0, ist, stateBytes, hipMemcpyDeviceToDevice, stream);
  (void)hipMemcpyAsync(s1, ist + BNH, stateBytes, hipMemcpyDeviceToDevice, stream);

  compute_A<<<kN, 256, 0, stream>>>(E, Ahh, All);
  // x diffusion through the MFMA path: Ax[bt,n,c] = sum_m A[n,m] x[bt,m,c]
  prep_x<<<dim3(16, 24), 256, 0, stream>>>(x, Vth, Vtl);
  diff_gemm<<<dim3(12, 8), 512, 0, stream>>>(Ahh, All, Vth, Vtl, Ax, 1);

  mkw2<<<dim3(128, 8), 256, 0, stream>>>(E, gw0, Wg0h, Wg0l, 128, 132, 160, 66, 1);
  mkw2<<<dim3(64, 8), 256, 0, stream>>>(E, uw0, Wu0h, Wu0l, 64, 132, 160, 66, 1);
  mkw2<<<dim3(128, 8), 256, 0, stream>>>(E, gw1, Wg1h, Wg1l, 128, 256, 256, 128, 0);
  mkw2<<<dim3(64, 8), 256, 0, stream>>>(E, uw1, Wu1h, Wu1l, 64, 256, 256, 128, 0);
  mkb<<<(kN * 128) / 256, 256, 0, stream>>>(E, gb0, Bg0, 128);
  mkb<<<(kN * 64) / 256, 256, 0, stream>>>(E, ub0, Bu0, 64);
  mkb<<<(kN * 128) / 256, 256, 0, stream>>>(E, gb1, Bg1, 128);
  mkb<<<(kN * 64) / 256, 256, 0, stream>>>(E, ub1, Bu1, 64);

  // bootstrap: d2 = A @ s0_init
  prep_split<<<dim3(16, kB, 1), 256, 0, stream>>>(s0, nullptr, nullptr, Vth, Vtl);
  diff_gemm<<<dim3(32, 8), 512, 0, stream>>>(Ahh, All, Vth, Vtl, d2, 6);

  for (int t = 0; t < kT; ++t) {
    // L0 gate (diffused state = d2 from previous step / bootstrap)
    StepPtrs Pg0{s0, s1, zr, x, Ax, d2, d2, d3};
    mfma_node<0, 128, 160><<<kN, 256, 0, stream>>>(Pg0, Wg0h, Wg0l, Bg0, zr, nullptr,
                                                   nullptr, nullptr, t);
    // G1 = A @ (z0*s0) -> dx
    prep_split<<<dim3(16, kB, 1), 256, 0, stream>>>(s0, nullptr, zr, Vth, Vtl);
    diff_gemm<<<dim3(32, 8), 512, 0, stream>>>(Ahh, All, Vth, Vtl, dx, 6);
    // L0 update: s0 <- h0; lasts[0] at t==T-1
    StepPtrs Pu0{s0, s1, zr, x, Ax, dx, d2, d3};
    mfma_node<1, 64, 160><<<kN, 256, 0, stream>>>(Pu0, Wu0h, Wu0l, Bu0, nullptr, s0,
                                                  nullptr, out + OUT0, t);
    // G2 = A @ [h0 ; s1] -> [d2 | d3]
    prep_split<<<dim3(16, kB, 2), 256, 0, stream>>>(s0, s1, nullptr, Vth, Vtl);
    diff_gemm<<<dim3(64, 8), 512, 0, stream>>>(Ahh, All, Vth, Vtl, d2, 6);
    // L1 gate
    StepPtrs P1g{s0, s1, zr, x, Ax, d2, d2, d3};
    mfma_node<2, 128, 256><<<kN, 256, 0, stream>>>(P1g, Wg1h, Wg1l, Bg1, zr, nullptr,
                                                   nullptr, nullptr, t);
    // G3 = A @ (z1*s1) -> dx
    prep_split<<<dim3(16, kB, 1), 256, 0, stream>>>(s1, nullptr, zr, Vth, Vtl);
    diff_gemm<<<dim3(32, 8), 512, 0, stream>>>(Ahh, All, Vth, Vtl, dx, 6);
    // L1 update: s1 <- h1; seq out; lasts[1] at t==T-1
    StepPtrs P1u{s0, s1, zr, x, Ax, d2, d2, dx};
    mfma_node<3, 64, 256><<<kN, 256, 0, stream>>>(P1u, Wu1h, Wu1l, Bu1, nullptr, s1, out,
                                                  out + OUT0 + BNH, t);
  }
}

// Round 7
// 3463.133 us; speedup vs baseline: 4.6714x; 1.1164x over previous
//
#include <hip/hip_runtime.h>
#include <cmath>

constexpr int kN = 1024;
constexpr int kB = 64;
constexpr int kT = 12;
constexpr int kH = 64;
constexpr int kE = 16;
constexpr long long OUT0 = (long long)kB * kT * kN * kH;  // 50331648
constexpr long long BNH = (long long)kB * kN * kH;        // 4194304

typedef __attribute__((ext_vector_type(8))) __bf16 bf16x8;
typedef __attribute__((ext_vector_type(4))) float f32x4;

struct StepPtrs {
  const float* s0;
  const float* s1;
  const float* zr;
  const float* x;
  const float* ax;
  const float* d1;
  const float* d2;
  const float* d3;
};

__device__ __forceinline__ float sig_(float v) { return 1.f / (1.f + expf(-v)); }

__device__ __forceinline__ unsigned short f2bf(float f) {
  unsigned u = __float_as_uint(f);
  unsigned r = u + 0x7FFFu + ((u >> 16) & 1u);
  return (unsigned short)(r >> 16);
}
__device__ __forceinline__ float bf2f(unsigned short s) {
  return __uint_as_float(((unsigned)s) << 16);
}

__device__ __forceinline__ void gload16(const void* g, void* l) {
  __builtin_amdgcn_global_load_lds((const __attribute__((address_space(1))) void*)g,
                                   (__attribute__((address_space(3))) void*)l, 16, 0, 0);
}

// ---- A = softmax(relu(E E^T), axis=1) -> row-major hi/lo bf16 split --------
__global__ void __launch_bounds__(256) compute_A(const float* __restrict__ E,
                                                 unsigned short* __restrict__ Ah,
                                                 unsigned short* __restrict__ Al) {
  int n = blockIdx.x, tx = threadIdx.x;
  __shared__ float En[kE];
  __shared__ float red[4];
  if (tx < kE) En[tx] = E[n * kE + tx];
  __syncthreads();
  float v[4];
  float mx = 0.f;
#pragma unroll
  for (int i = 0; i < 4; ++i) {
    int m = tx + i * 256;
    float s = 0.f;
#pragma unroll
    for (int d = 0; d < kE; ++d) s += En[d] * E[m * kE + d];
    s = fmaxf(s, 0.f);
    v[i] = s;
    mx = fmaxf(mx, s);
  }
#pragma unroll
  for (int off = 32; off; off >>= 1) mx = fmaxf(mx, __shfl_down(mx, off));
  int wid = tx >> 6, lane = tx & 63;
  if (lane == 0) red[wid] = mx;
  __syncthreads();
  mx = fmaxf(fmaxf(red[0], red[1]), fmaxf(red[2], red[3]));
  __syncthreads();
  float sum = 0.f;
#pragma unroll
  for (int i = 0; i < 4; ++i) {
    v[i] = expf(v[i] - mx);
    sum += v[i];
  }
#pragma unroll
  for (int off = 32; off; off >>= 1) sum += __shfl_down(sum, off);
  if (lane == 0) red[wid] = sum;
  __syncthreads();
  sum = red[0] + red[1] + red[2] + red[3];
  float inv = 1.f / sum;
#pragma unroll
  for (int i = 0; i < 4; ++i) {
    int m = tx + i * 256;
    float a = v[i] * inv;
    unsigned short h = f2bf(a);
    Ah[n * kN + m] = h;
    Al[n * kN + m] = f2bf(a - bf2f(h));
  }
}

// ---- per-node weights, TRANSPOSED + PADDED, single bf16 --------------------
// out Wh[((n*O + o)*KIp + ki], ki >= KI -> 0.
// mode 0 (L1, KI=256, Idim=128): ki<128 -> k=0,i=ki ; else k=1,i=ki-128
// mode 1 (L0, KI=132, Idim=66):  ki<128 -> k=ki>>6,i=(ki&63)+2 ;
//                                128..131 -> k=(ki-128)>>1, i=(ki-128)&1
__global__ void __launch_bounds__(256) mkw2(const float* __restrict__ E,
                                            const float* __restrict__ Wsrc,
                                            unsigned short* __restrict__ Wh,
                                            int O, int KI, int KIp, int Idim, int mode) {
  int o = blockIdx.x;
  int n0 = blockIdx.y * 128;
  int ki = threadIdx.x;
  __shared__ float Es[128][kE + 1];
  for (int idx = threadIdx.x; idx < 128 * kE; idx += 256)
    Es[idx >> 4][idx & 15] = E[(n0 + (idx >> 4)) * kE + (idx & 15)];
  __syncthreads();
  if (ki >= KIp) return;
  float w[kE];
  if (ki < KI) {
    int k, i;
    if (mode == 0) {
      k = ki >> 7;
      i = ki & 127;
    } else {
      if (ki < 128) {
        k = ki >> 6;
        i = (ki & 63) + 2;
      } else {
        k = (ki - 128) >> 1;
        i = (ki - 128) & 1;
      }
    }
#pragma unroll
    for (int d = 0; d < kE; ++d) w[d] = Wsrc[((d * 2 + k) * Idim + i) * O + o];
  } else {
#pragma unroll
    for (int d = 0; d < kE; ++d) w[d] = 0.f;
  }
  for (int nn = 0; nn < 128; ++nn) {
    float acc = 0.f;
#pragma unroll
    for (int d = 0; d < kE; ++d) acc += Es[nn][d] * w[d];
    Wh[((long long)(n0 + nn) * O + o) * KIp + ki] = f2bf(acc);
  }
}

// ---- per-node biases (fp32), parallel over (n,o): grid = kN*O/256 ----------
__global__ void __launch_bounds__(256) mkb(const float* __restrict__ E,
                                           const float* __restrict__ bsrc,
                                           float* __restrict__ out, int O) {
  int idx = blockIdx.x * 256 + threadIdx.x;
  int n = idx / O, o = idx - n * O;
  if (n >= kN) return;
  float acc = 0.f;
#pragma unroll
  for (int d = 0; d < kE; ++d) acc += E[n * kE + d] * bsrc[d * O + o];
  out[idx] = acc;
}

// ---- prep x: x[bt,m,c(2)] -> Xt hi/lo [col=bt*2+c][m] ----------------------
__global__ void __launch_bounds__(256) prep_x(const float* __restrict__ x,
                                              unsigned short* __restrict__ Vth,
                                              unsigned short* __restrict__ Vtl) {
  int m0 = blockIdx.x * 64, bt0 = blockIdx.y * 32, tid = threadIdx.x;
  __shared__ float T[64][65];
  for (int idx = tid; idx < 2048; idx += 256) {
    int mi = idx & 63, j = idx >> 6;
    float2 v = *(const float2*)&x[((long long)(bt0 + j) * kN + m0 + mi) * 2];
    T[j * 2 + 0][mi] = v.x;
    T[j * 2 + 1][mi] = v.y;
  }
  __syncthreads();
  for (int idx = tid; idx < 1024; idx += 256) {
    int cc = idx >> 4, mi4 = (idx & 15) * 4;
    float4 v = *(const float4*)&T[cc][mi4];
    ushort4 h, l;
    h.x = f2bf(v.x); l.x = f2bf(v.x - bf2f(h.x));
    h.y = f2bf(v.y); l.y = f2bf(v.y - bf2f(h.y));
    h.z = f2bf(v.z); l.z = f2bf(v.z - bf2f(h.z));
    h.w = f2bf(v.w); l.w = f2bf(v.w - bf2f(h.w));
    long long o = (long long)(bt0 * 2 + cc) * kN + m0 + mi4;
    *(ushort4*)&Vth[o] = h;
    *(ushort4*)&Vtl[o] = l;
  }
}

// ---- prep: V[b,m,c] (opt *mul) -> transposed hi/lo bf16 --------------------
__global__ void __launch_bounds__(256) prep_split(const float* __restrict__ srcA,
                                                  const float* __restrict__ srcB,
                                                  const float* __restrict__ mul,
                                                  unsigned short* __restrict__ Vth,
                                                  unsigned short* __restrict__ Vtl) {
  int b = blockIdx.y, m0 = blockIdx.x * 64, tid = threadIdx.x;
  int z = blockIdx.z;
  const float* src = z ? srcB : srcA;
  int colBase = z * 4096;
  __shared__ float T[64][65];
  for (int idx = tid; idx < 1024; idx += 256) {
    int mi = idx >> 4, c4 = (idx & 15) * 4;
    long long rowi = (long long)b * kN + m0 + mi;
    float4 v = *(const float4*)&src[rowi * 64 + c4];
    if (mul) {
      float4 mz = *(const float4*)&mul[rowi * 128 + c4];
      v.x *= mz.x; v.y *= mz.y; v.z *= mz.z; v.w *= mz.w;
    }
    T[c4 + 0][mi] = v.x;
    T[c4 + 1][mi] = v.y;
    T[c4 + 2][mi] = v.z;
    T[c4 + 3][mi] = v.w;
  }
  __syncthreads();
  for (int idx = tid; idx < 1024; idx += 256) {
    int c = idx >> 4, mi4 = (idx & 15) * 4;
    float4 v = *(const float4*)&T[c][mi4];
    ushort4 h, l;
    h.x = f2bf(v.x); l.x = f2bf(v.x - bf2f(h.x));
    h.y = f2bf(v.y); l.y = f2bf(v.y - bf2f(h.y));
    h.z = f2bf(v.z); l.z = f2bf(v.z - bf2f(h.z));
    h.w = f2bf(v.w); l.w = f2bf(v.w - bf2f(h.w));
    long long o = (long long)(colBase + b * 64 + c) * kN + m0 + mi4;
    *(ushort4*)&Vth[o] = h;
    *(ushort4*)&Vtl[o] = l;
  }
}

// ---- diffusion GEMM (2-phase double-buffered) -------------------------------
// out[((col>>sh)*kN + n) << sh | (col & (2^sh-1))] = sum_m A[n,m] V[m,col]
__global__ void __launch_bounds__(512, 4) diff_gemm(const unsigned short* __restrict__ Ah,
                                                    const unsigned short* __restrict__ Al,
                                                    const unsigned short* __restrict__ Vth,
                                                    const unsigned short* __restrict__ Vtl,
                                                    float* __restrict__ outp, int sh) {
  __shared__ __align__(16) unsigned short lds[2][16384];
  int tid = threadIdx.x;
  int lane = tid & 63;
  int q = lane >> 4, r16 = lane & 15;
  int wave = tid >> 6;
  int wm = wave >> 2, wn = wave & 3;
  int m0 = blockIdx.y * 128, n0 = blockIdx.x * 128;

  const unsigned short* gsrc[4];
  int ldst[4];
#pragma unroll
  for (int j = 0; j < 4; ++j) {
    int ci = j * 512 + tid;
    int tile = ci >> 9, idx = ci & 511;
    int row = idx >> 2, sp = idx & 3;
    int sl = sp ^ ((row >> 1) & 3);
    const unsigned short* s = (tile == 0) ? Ah : (tile == 1) ? Al : (tile == 2) ? Vth : Vtl;
    int gr = ((tile < 2) ? m0 : n0) + row;
    gsrc[j] = s + (long long)gr * kN + sl * 8;
    ldst[j] = ci * 8;
  }
  int aoff[4][2], voff[2][2];
#pragma unroll
  for (int fm = 0; fm < 4; ++fm) {
    int row = wm * 64 + fm * 16 + r16;
    int s = (q ^ ((row >> 1) & 3)) * 8;
    aoff[fm][0] = row * 32 + s;
    aoff[fm][1] = 4096 + row * 32 + s;
  }
#pragma unroll
  for (int fn = 0; fn < 2; ++fn) {
    int col = wn * 32 + fn * 16 + r16;
    int s = (q ^ ((col >> 1) & 3)) * 8;
    voff[fn][0] = 8192 + col * 32 + s;
    voff[fn][1] = 12288 + col * 32 + s;
  }
  f32x4 acc[4][2];
#pragma unroll
  for (int fm = 0; fm < 4; ++fm)
#pragma unroll
    for (int fn = 0; fn < 2; ++fn) acc[fm][fn] = (f32x4){0.f, 0.f, 0.f, 0.f};

  auto STAGE = [&](int buf, int kt) {
#pragma unroll
    for (int j = 0; j < 4; ++j) gload16(gsrc[j] + kt * 32, &lds[buf][ldst[j]]);
  };
  auto COMPUTE = [&](int buf) {
    const unsigned short* L = &lds[buf][0];
    bf16x8 ah[4], al[4], vh[2], vl[2];
#pragma unroll
    for (int fm = 0; fm < 4; ++fm) {
      ah[fm] = *(const bf16x8*)&L[aoff[fm][0]];
      al[fm] = *(const bf16x8*)&L[aoff[fm][1]];
    }
#pragma unroll
    for (int fn = 0; fn < 2; ++fn) {
      vh[fn] = *(const bf16x8*)&L[voff[fn][0]];
      vl[fn] = *(const bf16x8*)&L[voff[fn][1]];
    }
#pragma unroll
    for (int fm = 0; fm < 4; ++fm)
#pragma unroll
      for (int fn = 0; fn < 2; ++fn) {
        acc[fm][fn] =
            __builtin_amdgcn_mfma_f32_16x16x32_bf16(ah[fm], vh[fn], acc[fm][fn], 0, 0, 0);
        acc[fm][fn] =
            __builtin_amdgcn_mfma_f32_16x16x32_bf16(ah[fm], vl[fn], acc[fm][fn], 0, 0, 0);
        acc[fm][fn] =
            __builtin_amdgcn_mfma_f32_16x16x32_bf16(al[fm], vh[fn], acc[fm][fn], 0, 0, 0);
      }
  };

  STAGE(0, 0);
  asm volatile("s_waitcnt vmcnt(0)" ::: "memory");
  __builtin_amdgcn_s_barrier();
#pragma unroll 1
  for (int kt = 0; kt < 30; kt += 2) {
    STAGE(1, kt + 1);
    COMPUTE(0);
    asm volatile("s_waitcnt vmcnt(0)" ::: "memory");
    __builtin_amdgcn_s_barrier();
    STAGE(0, kt + 2);
    COMPUTE(1);
    asm volatile("s_waitcnt vmcnt(0)" ::: "memory");
    __builtin_amdgcn_s_barrier();
  }
  STAGE(1, 31);
  COMPUTE(0);
  asm volatile("s_waitcnt vmcnt(0)" ::: "memory");
  __builtin_amdgcn_s_barrier();
  COMPUTE(1);

  int msk = (1 << sh) - 1;
#pragma unroll
  for (int fm = 0; fm < 4; ++fm)
#pragma unroll
    for (int fn = 0; fn < 2; ++fn) {
      int nrow = m0 + wm * 64 + fm * 16 + q * 4;
      int col = n0 + wn * 32 + fn * 16 + r16;
      long long b = col >> sh;
      int c = col & msk;
#pragma unroll
      for (int r = 0; r < 4; ++r)
        outp[(((b * kN + nrow + r)) << sh) + c] = acc[fm][fn][r];
    }
}

// ---- per-node MFMA GEMM + fused gate epilogue -------------------------------
// block = node n, 4 waves. C[64b x O] = X[64b x KIp] @ Wn[KIp x O].
// X split hi/lo (2 MFMA passes vs bf16 W); W single bf16 (HBM-traffic bound).
template <int VAR, int O, int KIp>
__global__ void __launch_bounds__(256, 2) mfma_node(StepPtrs P,
                                                    const unsigned short* __restrict__ Wh,
                                                    const float* __restrict__ bias,
                                                    float* __restrict__ zr_out,
                                                    float* __restrict__ state_out,
                                                    float* __restrict__ seq_out,
                                                    float* __restrict__ last_out, int t) {
  constexpr int S = KIp + 8;  // LDS row stride (elements)
  constexpr int NKT = KIp / 32;
  constexpr int NF = (O == 128) ? 2 : 1;
  __shared__ __align__(16) unsigned short Xh[64 * S];
  __shared__ __align__(16) unsigned short Xl[64 * S];
  int n = blockIdx.x;
  int tid = threadIdx.x;

  auto put4 = [&](int b, int c, float4 v) {
    ushort4 h, l;
    h.x = f2bf(v.x); l.x = f2bf(v.x - bf2f(h.x));
    h.y = f2bf(v.y); l.y = f2bf(v.y - bf2f(h.y));
    h.z = f2bf(v.z); l.z = f2bf(v.z - bf2f(h.z));
    h.w = f2bf(v.w); l.w = f2bf(v.w - bf2f(h.w));
    *(ushort4*)&Xh[b * S + c] = h;
    *(ushort4*)&Xl[b * S + c] = l;
  };

  if constexpr (VAR == 0 || VAR == 1) {
    // X = [s0(*z) | d1 | x_t(2) | ax(2) | pad..160)
    for (int idx = tid; idx < 1024; idx += 256) {
      int b = idx >> 4, c4 = (idx & 15) << 2;
      long long bn = (long long)b * kN + n;
      float4 v0 = *(const float4*)&P.s0[bn * 64 + c4];
      if (VAR == 1) {
        float4 z = *(const float4*)&P.zr[bn * 128 + c4];
        v0.x *= z.x; v0.y *= z.y; v0.z *= z.z; v0.w *= z.w;
      }
      put4(b, c4, v0);
      float4 v1 = *(const float4*)&P.d1[bn * 64 + c4];
      put4(b, 64 + c4, v1);
    }
    if (tid < 128) {
      int b = tid >> 1, c = tid & 1;
      long long btn = ((long long)b * kT + t) * kN + n;
      float vx = P.x[btn * 2 + c];
      float va = P.ax[btn * 2 + c];
      unsigned short h = f2bf(vx);
      Xh[b * S + 128 + c] = h;
      Xl[b * S + 128 + c] = f2bf(vx - bf2f(h));
      h = f2bf(va);
      Xh[b * S + 130 + c] = h;
      Xl[b * S + 130 + c] = f2bf(va - bf2f(h));
    }
    for (int idx = tid; idx < 448; idx += 256) {  // zero pad ki 132..159
      int b = idx / 7, c = 132 + (idx % 7) * 4;
      ushort4 zz = {0, 0, 0, 0};
      *(ushort4*)&Xh[b * S + c] = zz;
      *(ushort4*)&Xl[b * S + c] = zz;
    }
  } else {
    // X = [s0 | s1(*z) | d2 | d3]  (256)
    for (int idx = tid; idx < 1024; idx += 256) {
      int b = idx >> 4, c4 = (idx & 15) << 2;
      long long bn = (long long)b * kN + n;
      float4 v0 = *(const float4*)&P.s0[bn * 64 + c4];
      put4(b, c4, v0);
      float4 v1 = *(const float4*)&P.s1[bn * 64 + c4];
      if (VAR == 3) {
        float4 z = *(const float4*)&P.zr[bn * 128 + c4];
        v1.x *= z.x; v1.y *= z.y; v1.z *= z.z; v1.w *= z.w;
      }
      put4(b, 64 + c4, v1);
      float4 v2 = *(const float4*)&P.d2[bn * 64 + c4];
      put4(b, 128 + c4, v2);
      float4 v3 = *(const float4*)&P.d3[bn * 64 + c4];
      put4(b, 192 + c4, v3);
    }
  }
  __syncthreads();

  int lane = tid & 63, wave = tid >> 6;
  int q = lane >> 4, r16 = lane & 15;
  int colbase = (O == 128) ? wave * 32 : wave * 16;
  f32x4 acc[4][NF];
#pragma unroll
  for (int fm = 0; fm < 4; ++fm)
#pragma unroll
    for (int fn = 0; fn < NF; ++fn) acc[fm][fn] = (f32x4){0.f, 0.f, 0.f, 0.f};

#pragma unroll 2
  for (int kt = 0; kt < NKT; ++kt) {
    int kb = kt * 32 + q * 8;
    bf16x8 xh[4], xl[4], wh[NF];
#pragma unroll
    for (int fm = 0; fm < 4; ++fm) {
      xh[fm] = *(const bf16x8*)&Xh[(fm * 16 + r16) * S + kb];
      xl[fm] = *(const bf16x8*)&Xl[(fm * 16 + r16) * S + kb];
    }
#pragma unroll
    for (int fn = 0; fn < NF; ++fn) {
      int o = colbase + fn * 16 + r16;
      wh[fn] = *(const bf16x8*)&Wh[((long long)n * O + o) * KIp + kb];
    }
#pragma unroll
    for (int fm = 0; fm < 4; ++fm)
#pragma unroll
      for (int fn = 0; fn < NF; ++fn) {
        acc[fm][fn] =
            __builtin_amdgcn_mfma_f32_16x16x32_bf16(xh[fm], wh[fn], acc[fm][fn], 0, 0, 0);
        acc[fm][fn] =
            __builtin_amdgcn_mfma_f32_16x16x32_bf16(xl[fm], wh[fn], acc[fm][fn], 0, 0, 0);
      }
  }

  if constexpr (O == 128) {  // gate: zr = sigmoid(acc + bias)
#pragma unroll
    for (int fn = 0; fn < NF; ++fn) {
      int o = colbase + fn * 16 + r16;
      float bb = bias[n * 128 + o];
#pragma unroll
      for (int fm = 0; fm < 4; ++fm) {
#pragma unroll
        for (int r = 0; r < 4; ++r) {
          int b = fm * 16 + q * 4 + r;
          zr_out[((long long)b * kN + n) * 128 + o] = sig_(acc[fm][fn][r] + bb);
        }
      }
    }
  } else {  // update: h = r*s + (1-r)*tanh(acc + bias)
    const float* sptr = (VAR == 1) ? P.s0 : P.s1;
    int o = colbase + r16;
    float bb = bias[n * 64 + o];
#pragma unroll
    for (int fm = 0; fm < 4; ++fm) {
#pragma unroll
      for (int r = 0; r < 4; ++r) {
        int b = fm * 16 + q * 4 + r;
        long long bn = (long long)b * kN + n;
        float rr = P.zr[bn * 128 + 64 + o];
        float ss = sptr[bn * 64 + o];
        float h = rr * ss + (1.f - rr) * tanhf(acc[fm][0][r] + bb);
        state_out[bn * 64 + o] = h;
        if constexpr (VAR == 3) {
          seq_out[(((long long)b * kT + t) * kN + n) * 64 + o] = h;
        }
        if (t == kT - 1) last_out[bn * 64 + o] = h;
      }
    }
  }
}

extern "C" void kernel_launch(void* const* d_in, const int* in_sizes, int n_in, void* d_out,
                              int out_size, void* d_ws, size_t ws_size, hipStream_t stream) {
  (void)in_sizes; (void)n_in; (void)out_size; (void)ws_size;
  const float* x   = (const float*)d_in[0];
  const float* ist = (const float*)d_in[1];
  const float* E   = (const float*)d_in[2];
  const float* gw0 = (const float*)d_in[3];
  const float* gb0 = (const float*)d_in[4];
  const float* uw0 = (const float*)d_in[5];
  const float* ub0 = (const float*)d_in[6];
  const float* gw1 = (const float*)d_in[7];
  const float* gb1 = (const float*)d_in[8];
  const float* uw1 = (const float*)d_in[9];
  const float* ub1 = (const float*)d_in[10];
  float* out = (float*)d_out;

  char* base = (char*)d_ws;
  size_t off = 0;
  auto alloc = [&](size_t bytes) {
    char* p = base + off;
    off += (bytes + 1023) & ~(size_t)1023;
    return p;
  };
  unsigned short* Vth = (unsigned short*)alloc((size_t)8192 * kN * 2);
  unsigned short* Vtl = (unsigned short*)alloc((size_t)8192 * kN * 2);
  unsigned short* Ahh = (unsigned short*)alloc((size_t)kN * kN * 2);
  unsigned short* All = (unsigned short*)alloc((size_t)kN * kN * 2);
  float* Ax = (float*)alloc((size_t)kB * kT * kN * 2 * 4);
  unsigned short* Wg0h = (unsigned short*)alloc((size_t)kN * 128 * 160 * 2);
  unsigned short* Wu0h = (unsigned short*)alloc((size_t)kN * 64 * 160 * 2);
  unsigned short* Wg1h = (unsigned short*)alloc((size_t)kN * 128 * 256 * 2);
  unsigned short* Wu1h = (unsigned short*)alloc((size_t)kN * 64 * 256 * 2);
  float* Bg0 = (float*)alloc((size_t)kN * 128 * 4);
  float* Bu0 = (float*)alloc((size_t)kN * 64 * 4);
  float* Bg1 = (float*)alloc((size_t)kN * 128 * 4);
  float* Bu1 = (float*)alloc((size_t)kN * 64 * 4);
  float* s0 = (float*)alloc((size_t)BNH * 4);
  float* s1 = (float*)alloc((size_t)BNH * 4);
  float* dx = (float*)alloc((size_t)BNH * 4);
  float* dd = (float*)alloc((size_t)BNH * 2 * 4);  // [d2 | d3]
  float* zr = (float*)alloc((size_t)kB * kN * 128 * 4);
  float* d2 = dd;
  float* d3 = dd + BNH;

  const size_t stateBytes = (size_t)BNH * sizeof(float);
  (void)hipMemcpyAsync(s0, ist, stateBytes, hipMemcpyDeviceToDevice, stream);
  (void)hipMemcpyAsync(s1, ist + BNH, stateBytes, hipMemcpyDeviceToDevice, stream);

  compute_A<<<kN, 256, 0, stream>>>(E, Ahh, All);
  // x diffusion through the MFMA path: Ax[bt,n,c] = sum_m A[n,m] x[bt,m,c]
  prep_x<<<dim3(16, 24), 256, 0, stream>>>(x, Vth, Vtl);
  diff_gemm<<<dim3(12, 8), 512, 0, stream>>>(Ahh, All, Vth, Vtl, Ax, 1);

  mkw2<<<dim3(128, 8), 256, 0, stream>>>(E, gw0, Wg0h, 128, 132, 160, 66, 1);
  mkw2<<<dim3(64, 8), 256, 0, stream>>>(E, uw0, Wu0h, 64, 132, 160, 66, 1);
  mkw2<<<dim3(128, 8), 256, 0, stream>>>(E, gw1, Wg1h, 128, 256, 256, 128, 0);
  mkw2<<<dim3(64, 8), 256, 0, stream>>>(E, uw1, Wu1h, 64, 256, 256, 128, 0);
  mkb<<<(kN * 128) / 256, 256, 0, stream>>>(E, gb0, Bg0, 128);
  mkb<<<(kN * 64) / 256, 256, 0, stream>>>(E, ub0, Bu0, 64);
  mkb<<<(kN * 128) / 256, 256, 0, stream>>>(E, gb1, Bg1, 128);
  mkb<<<(kN * 64) / 256, 256, 0, stream>>>(E, ub1, Bu1, 64);

  // bootstrap: d2 = A @ s0_init
  prep_split<<<dim3(16, kB, 1), 256, 0, stream>>>(s0, nullptr, nullptr, Vth, Vtl);
  diff_gemm<<<dim3(32, 8), 512, 0, stream>>>(Ahh, All, Vth, Vtl, d2, 6);

  for (int t = 0; t < kT; ++t) {
    // L0 gate (diffused state = d2 from previous step / bootstrap)
    StepPtrs Pg0{s0, s1, zr, x, Ax, d2, d2, d3};
    mfma_node<0, 128, 160><<<kN, 256, 0, stream>>>(Pg0, Wg0h, Bg0, zr, nullptr,
                                                   nullptr, nullptr, t);
    // G1 = A @ (z0*s0) -> dx
    prep_split<<<dim3(16, kB, 1), 256, 0, stream>>>(s0, nullptr, zr, Vth, Vtl);
    diff_gemm<<<dim3(32, 8), 512, 0, stream>>>(Ahh, All, Vth, Vtl, dx, 6);
    // L0 update: s0 <- h0; lasts[0] at t==T-1
    StepPtrs Pu0{s0, s1, zr, x, Ax, dx, d2, d3};
    mfma_node<1, 64, 160><<<kN, 256, 0, stream>>>(Pu0, Wu0h, Bu0, nullptr, s0,
                                                  nullptr, out + OUT0, t);
    // G2 = A @ [h0 ; s1] -> [d2 | d3]
    prep_split<<<dim3(16, kB, 2), 256, 0, stream>>>(s0, s1, nullptr, Vth, Vtl);
    diff_gemm<<<dim3(64, 8), 512, 0, stream>>>(Ahh, All, Vth, Vtl, d2, 6);
    // L1 gate
    StepPtrs P1g{s0, s1, zr, x, Ax, d2, d2, d3};
    mfma_node<2, 128, 256><<<kN, 256, 0, stream>>>(P1g, Wg1h, Bg1, zr, nullptr,
                                                   nullptr, nullptr, t);
    // G3 = A @ (z1*s1) -> dx
    prep_split<<<dim3(16, kB, 1), 256, 0, stream>>>(s1, nullptr, zr, Vth, Vtl);
    diff_gemm<<<dim3(32, 8), 512, 0, stream>>>(Ahh, All, Vth, Vtl, dx, 6);
    // L1 update: s1 <- h1; seq out; lasts[1] at t==T-1
    StepPtrs P1u{s0, s1, zr, x, Ax, d2, d2, dx};
    mfma_node<3, 64, 256><<<kN, 256, 0, stream>>>(P1u, Wu1h, Bu1, nullptr, s1, out,
                                                  out + OUT0 + BNH, t);
  }
}

// Round 8
// 2914.698 us; speedup vs baseline: 5.5503x; 1.1882x over previous
//
#include <hip/hip_runtime.h>
#include <cmath>

constexpr int kN = 1024;
constexpr int kB = 64;
constexpr int kT = 12;
constexpr int kH = 64;
constexpr int kE = 16;
constexpr long long OUT0 = (long long)kB * kT * kN * kH;  // 50331648
constexpr long long BNH = (long long)kB * kN * kH;        // 4194304

typedef __attribute__((ext_vector_type(8))) __bf16 bf16x8;
typedef __attribute__((ext_vector_type(4))) float f32x4;

struct StepPtrs {
  const float* s0;
  const float* s1;
  const float* zr;
  const float* x;
  const float* ax;
  const float* d1;
  const float* d2;
  const float* d3;
};

__device__ __forceinline__ float sig_(float v) { return 1.f / (1.f + expf(-v)); }

__device__ __forceinline__ unsigned short f2bf(float f) {
  unsigned u = __float_as_uint(f);
  unsigned r = u + 0x7FFFu + ((u >> 16) & 1u);
  return (unsigned short)(r >> 16);
}
__device__ __forceinline__ float bf2f(unsigned short s) {
  return __uint_as_float(((unsigned)s) << 16);
}

__device__ __forceinline__ void gload16(const void* g, void* l) {
  __builtin_amdgcn_global_load_lds((const __attribute__((address_space(1))) void*)g,
                                   (__attribute__((address_space(3))) void*)l, 16, 0, 0);
}

// ---- A = softmax(relu(E E^T), axis=1) -> row-major bf16 --------------------
__global__ void __launch_bounds__(256) compute_A(const float* __restrict__ E,
                                                 unsigned short* __restrict__ Ah) {
  int n = blockIdx.x, tx = threadIdx.x;
  __shared__ float En[kE];
  __shared__ float red[4];
  if (tx < kE) En[tx] = E[n * kE + tx];
  __syncthreads();
  float v[4];
  float mx = 0.f;
#pragma unroll
  for (int i = 0; i < 4; ++i) {
    int m = tx + i * 256;
    float s = 0.f;
#pragma unroll
    for (int d = 0; d < kE; ++d) s += En[d] * E[m * kE + d];
    s = fmaxf(s, 0.f);
    v[i] = s;
    mx = fmaxf(mx, s);
  }
#pragma unroll
  for (int off = 32; off; off >>= 1) mx = fmaxf(mx, __shfl_down(mx, off));
  int wid = tx >> 6, lane = tx & 63;
  if (lane == 0) red[wid] = mx;
  __syncthreads();
  mx = fmaxf(fmaxf(red[0], red[1]), fmaxf(red[2], red[3]));
  __syncthreads();
  float sum = 0.f;
#pragma unroll
  for (int i = 0; i < 4; ++i) {
    v[i] = expf(v[i] - mx);
    sum += v[i];
  }
#pragma unroll
  for (int off = 32; off; off >>= 1) sum += __shfl_down(sum, off);
  if (lane == 0) red[wid] = sum;
  __syncthreads();
  sum = red[0] + red[1] + red[2] + red[3];
  float inv = 1.f / sum;
#pragma unroll
  for (int i = 0; i < 4; ++i) {
    int m = tx + i * 256;
    Ah[n * kN + m] = f2bf(v[i] * inv);
  }
}

// ---- per-node weights, TRANSPOSED + PADDED, single bf16 --------------------
__global__ void __launch_bounds__(256) mkw2(const float* __restrict__ E,
                                            const float* __restrict__ Wsrc,
                                            unsigned short* __restrict__ Wh,
                                            int O, int KI, int KIp, int Idim, int mode) {
  int o = blockIdx.x;
  int n0 = blockIdx.y * 128;
  int ki = threadIdx.x;
  __shared__ float Es[128][kE + 1];
  for (int idx = threadIdx.x; idx < 128 * kE; idx += 256)
    Es[idx >> 4][idx & 15] = E[(n0 + (idx >> 4)) * kE + (idx & 15)];
  __syncthreads();
  if (ki >= KIp) return;
  float w[kE];
  if (ki < KI) {
    int k, i;
    if (mode == 0) {
      k = ki >> 7;
      i = ki & 127;
    } else {
      if (ki < 128) {
        k = ki >> 6;
        i = (ki & 63) + 2;
      } else {
        k = (ki - 128) >> 1;
        i = (ki - 128) & 1;
      }
    }
#pragma unroll
    for (int d = 0; d < kE; ++d) w[d] = Wsrc[((d * 2 + k) * Idim + i) * O + o];
  } else {
#pragma unroll
    for (int d = 0; d < kE; ++d) w[d] = 0.f;
  }
  for (int nn = 0; nn < 128; ++nn) {
    float acc = 0.f;
#pragma unroll
    for (int d = 0; d < kE; ++d) acc += Es[nn][d] * w[d];
    Wh[((long long)(n0 + nn) * O + o) * KIp + ki] = f2bf(acc);
  }
}

// ---- per-node biases (fp32), parallel over (n,o) ---------------------------
__global__ void __launch_bounds__(256) mkb(const float* __restrict__ E,
                                           const float* __restrict__ bsrc,
                                           float* __restrict__ out, int O) {
  int idx = blockIdx.x * 256 + threadIdx.x;
  int n = idx / O, o = idx - n * O;
  if (n >= kN) return;
  float acc = 0.f;
#pragma unroll
  for (int d = 0; d < kE; ++d) acc += E[n * kE + d] * bsrc[d * O + o];
  out[idx] = acc;
}

// ---- prep x: x[bt,m,c(2)] -> Xt bf16 [col=bt*2+c][m] -----------------------
__global__ void __launch_bounds__(256) prep_x(const float* __restrict__ x,
                                              unsigned short* __restrict__ Vth) {
  int m0 = blockIdx.x * 64, bt0 = blockIdx.y * 32, tid = threadIdx.x;
  __shared__ float T[64][65];
  for (int idx = tid; idx < 2048; idx += 256) {
    int mi = idx & 63, j = idx >> 6;
    float2 v = *(const float2*)&x[((long long)(bt0 + j) * kN + m0 + mi) * 2];
    T[j * 2 + 0][mi] = v.x;
    T[j * 2 + 1][mi] = v.y;
  }
  __syncthreads();
  for (int idx = tid; idx < 1024; idx += 256) {
    int cc = idx >> 4, mi4 = (idx & 15) * 4;
    float4 v = *(const float4*)&T[cc][mi4];
    ushort4 h;
    h.x = f2bf(v.x);
    h.y = f2bf(v.y);
    h.z = f2bf(v.z);
    h.w = f2bf(v.w);
    *(ushort4*)&Vth[(long long)(bt0 * 2 + cc) * kN + m0 + mi4] = h;
  }
}

// ---- prep: V[b,m,c] (opt *mul) -> transposed bf16 --------------------------
__global__ void __launch_bounds__(256) prep_split(const float* __restrict__ srcA,
                                                  const float* __restrict__ srcB,
                                                  const float* __restrict__ mul,
                                                  unsigned short* __restrict__ Vth) {
  int b = blockIdx.y, m0 = blockIdx.x * 64, tid = threadIdx.x;
  int z = blockIdx.z;
  const float* src = z ? srcB : srcA;
  int colBase = z * 4096;
  __shared__ float T[64][65];
  for (int idx = tid; idx < 1024; idx += 256) {
    int mi = idx >> 4, c4 = (idx & 15) * 4;
    long long rowi = (long long)b * kN + m0 + mi;
    float4 v = *(const float4*)&src[rowi * 64 + c4];
    if (mul) {
      float4 mz = *(const float4*)&mul[rowi * 128 + c4];
      v.x *= mz.x; v.y *= mz.y; v.z *= mz.z; v.w *= mz.w;
    }
    T[c4 + 0][mi] = v.x;
    T[c4 + 1][mi] = v.y;
    T[c4 + 2][mi] = v.z;
    T[c4 + 3][mi] = v.w;
  }
  __syncthreads();
  for (int idx = tid; idx < 1024; idx += 256) {
    int c = idx >> 4, mi4 = (idx & 15) * 4;
    float4 v = *(const float4*)&T[c][mi4];
    ushort4 h;
    h.x = f2bf(v.x);
    h.y = f2bf(v.y);
    h.z = f2bf(v.z);
    h.w = f2bf(v.w);
    *(ushort4*)&Vth[(long long)(colBase + b * 64 + c) * kN + m0 + mi4] = h;
  }
}

// ---- diffusion GEMM (pure bf16, 1 pass, 2-phase double-buffered) ------------
// out[((col>>sh)*kN + n) << sh | (col & (2^sh-1))] = sum_m A[n,m] V[m,col]
__global__ void __launch_bounds__(512, 4) diff_gemm(const unsigned short* __restrict__ Ah,
                                                    const unsigned short* __restrict__ Vth,
                                                    float* __restrict__ outp, int sh) {
  __shared__ __align__(16) unsigned short lds[2][8192];
  int tid = threadIdx.x;
  int lane = tid & 63;
  int q = lane >> 4, r16 = lane & 15;
  int wave = tid >> 6;
  int wm = wave >> 2, wn = wave & 3;
  int m0 = blockIdx.y * 128, n0 = blockIdx.x * 128;

  const unsigned short* gsrc[2];
  int ldst[2];
#pragma unroll
  for (int j = 0; j < 2; ++j) {
    int ci = j * 512 + tid;
    int tile = ci >> 9, idx = ci & 511;
    int row = idx >> 2, sp = idx & 3;
    int sl = sp ^ ((row >> 1) & 3);
    const unsigned short* s = tile ? Vth : Ah;
    int gr = (tile ? n0 : m0) + row;
    gsrc[j] = s + (long long)gr * kN + sl * 8;
    ldst[j] = ci * 8;
  }
  int aoff[4], voff[2];
#pragma unroll
  for (int fm = 0; fm < 4; ++fm) {
    int row = wm * 64 + fm * 16 + r16;
    aoff[fm] = row * 32 + (q ^ ((row >> 1) & 3)) * 8;
  }
#pragma unroll
  for (int fn = 0; fn < 2; ++fn) {
    int col = wn * 32 + fn * 16 + r16;
    voff[fn] = 4096 + col * 32 + (q ^ ((col >> 1) & 3)) * 8;
  }
  f32x4 acc[4][2];
#pragma unroll
  for (int fm = 0; fm < 4; ++fm)
#pragma unroll
    for (int fn = 0; fn < 2; ++fn) acc[fm][fn] = (f32x4){0.f, 0.f, 0.f, 0.f};

  auto STAGE = [&](int buf, int kt) {
#pragma unroll
    for (int j = 0; j < 2; ++j) gload16(gsrc[j] + kt * 32, &lds[buf][ldst[j]]);
  };
  auto COMPUTE = [&](int buf) {
    const unsigned short* L = &lds[buf][0];
    bf16x8 ah[4], vh[2];
#pragma unroll
    for (int fm = 0; fm < 4; ++fm) ah[fm] = *(const bf16x8*)&L[aoff[fm]];
#pragma unroll
    for (int fn = 0; fn < 2; ++fn) vh[fn] = *(const bf16x8*)&L[voff[fn]];
#pragma unroll
    for (int fm = 0; fm < 4; ++fm)
#pragma unroll
      for (int fn = 0; fn < 2; ++fn)
        acc[fm][fn] =
            __builtin_amdgcn_mfma_f32_16x16x32_bf16(ah[fm], vh[fn], acc[fm][fn], 0, 0, 0);
  };

  STAGE(0, 0);
  asm volatile("s_waitcnt vmcnt(0)" ::: "memory");
  __builtin_amdgcn_s_barrier();
#pragma unroll 1
  for (int kt = 0; kt < 30; kt += 2) {
    STAGE(1, kt + 1);
    COMPUTE(0);
    asm volatile("s_waitcnt vmcnt(0)" ::: "memory");
    __builtin_amdgcn_s_barrier();
    STAGE(0, kt + 2);
    COMPUTE(1);
    asm volatile("s_waitcnt vmcnt(0)" ::: "memory");
    __builtin_amdgcn_s_barrier();
  }
  STAGE(1, 31);
  COMPUTE(0);
  asm volatile("s_waitcnt vmcnt(0)" ::: "memory");
  __builtin_amdgcn_s_barrier();
  COMPUTE(1);

  int msk = (1 << sh) - 1;
#pragma unroll
  for (int fm = 0; fm < 4; ++fm)
#pragma unroll
    for (int fn = 0; fn < 2; ++fn) {
      int nrow = m0 + wm * 64 + fm * 16 + q * 4;
      int col = n0 + wn * 32 + fn * 16 + r16;
      long long b = col >> sh;
      int c = col & msk;
#pragma unroll
      for (int r = 0; r < 4; ++r)
        outp[(((b * kN + nrow + r)) << sh) + c] = acc[fm][fn][r];
    }
}

// ---- per-node MFMA GEMM + fused gate epilogue -------------------------------
// block = node n, 4 waves. C[64b x O] = X[64b x KIp] @ Wn[KIp x O].
// X split hi/lo (2 MFMA passes vs bf16 W); W single bf16 (HBM/L3-bound).
template <int VAR, int O, int KIp>
__global__ void __launch_bounds__(256, 2) mfma_node(StepPtrs P,
                                                    const unsigned short* __restrict__ Wh,
                                                    const float* __restrict__ bias,
                                                    float* __restrict__ zr_out,
                                                    float* __restrict__ state_out,
                                                    float* __restrict__ seq_out,
                                                    float* __restrict__ last_out, int t) {
  constexpr int S = KIp + 8;  // LDS row stride (elements)
  constexpr int NKT = KIp / 32;
  constexpr int NF = (O == 128) ? 2 : 1;
  __shared__ __align__(16) unsigned short Xh[64 * S];
  __shared__ __align__(16) unsigned short Xl[64 * S];
  int n = blockIdx.x;
  int tid = threadIdx.x;

  auto put4 = [&](int b, int c, float4 v) {
    ushort4 h, l;
    h.x = f2bf(v.x); l.x = f2bf(v.x - bf2f(h.x));
    h.y = f2bf(v.y); l.y = f2bf(v.y - bf2f(h.y));
    h.z = f2bf(v.z); l.z = f2bf(v.z - bf2f(h.z));
    h.w = f2bf(v.w); l.w = f2bf(v.w - bf2f(h.w));
    *(ushort4*)&Xh[b * S + c] = h;
    *(ushort4*)&Xl[b * S + c] = l;
  };

  if constexpr (VAR == 0 || VAR == 1) {
    // X = [s0(*z) | d1 | x_t(2) | ax(2) | pad..160)
    for (int idx = tid; idx < 1024; idx += 256) {
      int b = idx >> 4, c4 = (idx & 15) << 2;
      long long bn = (long long)b * kN + n;
      float4 v0 = *(const float4*)&P.s0[bn * 64 + c4];
      if (VAR == 1) {
        float4 z = *(const float4*)&P.zr[bn * 128 + c4];
        v0.x *= z.x; v0.y *= z.y; v0.z *= z.z; v0.w *= z.w;
      }
      put4(b, c4, v0);
      float4 v1 = *(const float4*)&P.d1[bn * 64 + c4];
      put4(b, 64 + c4, v1);
    }
    if (tid < 128) {
      int b = tid >> 1, c = tid & 1;
      long long btn = ((long long)b * kT + t) * kN + n;
      float vx = P.x[btn * 2 + c];
      float va = P.ax[btn * 2 + c];
      unsigned short h = f2bf(vx);
      Xh[b * S + 128 + c] = h;
      Xl[b * S + 128 + c] = f2bf(vx - bf2f(h));
      h = f2bf(va);
      Xh[b * S + 130 + c] = h;
      Xl[b * S + 130 + c] = f2bf(va - bf2f(h));
    }
    for (int idx = tid; idx < 448; idx += 256) {  // zero pad ki 132..159
      int b = idx / 7, c = 132 + (idx % 7) * 4;
      ushort4 zz = {0, 0, 0, 0};
      *(ushort4*)&Xh[b * S + c] = zz;
      *(ushort4*)&Xl[b * S + c] = zz;
    }
  } else {
    // X = [s0 | s1(*z) | d2 | d3]  (256)
    for (int idx = tid; idx < 1024; idx += 256) {
      int b = idx >> 4, c4 = (idx & 15) << 2;
      long long bn = (long long)b * kN + n;
      float4 v0 = *(const float4*)&P.s0[bn * 64 + c4];
      put4(b, c4, v0);
      float4 v1 = *(const float4*)&P.s1[bn * 64 + c4];
      if (VAR == 3) {
        float4 z = *(const float4*)&P.zr[bn * 128 + c4];
        v1.x *= z.x; v1.y *= z.y; v1.z *= z.z; v1.w *= z.w;
      }
      put4(b, 64 + c4, v1);
      float4 v2 = *(const float4*)&P.d2[bn * 64 + c4];
      put4(b, 128 + c4, v2);
      float4 v3 = *(const float4*)&P.d3[bn * 64 + c4];
      put4(b, 192 + c4, v3);
    }
  }
  __syncthreads();

  int lane = tid & 63, wave = tid >> 6;
  int q = lane >> 4, r16 = lane & 15;
  int colbase = (O == 128) ? wave * 32 : wave * 16;
  f32x4 acc[4][NF];
#pragma unroll
  for (int fm = 0; fm < 4; ++fm)
#pragma unroll
    for (int fn = 0; fn < NF; ++fn) acc[fm][fn] = (f32x4){0.f, 0.f, 0.f, 0.f};

#pragma unroll 2
  for (int kt = 0; kt < NKT; ++kt) {
    int kb = kt * 32 + q * 8;
    bf16x8 xh[4], xl[4], wh[NF];
#pragma unroll
    for (int fm = 0; fm < 4; ++fm) {
      xh[fm] = *(const bf16x8*)&Xh[(fm * 16 + r16) * S + kb];
      xl[fm] = *(const bf16x8*)&Xl[(fm * 16 + r16) * S + kb];
    }
#pragma unroll
    for (int fn = 0; fn < NF; ++fn) {
      int o = colbase + fn * 16 + r16;
      wh[fn] = *(const bf16x8*)&Wh[((long long)n * O + o) * KIp + kb];
    }
#pragma unroll
    for (int fm = 0; fm < 4; ++fm)
#pragma unroll
      for (int fn = 0; fn < NF; ++fn) {
        acc[fm][fn] =
            __builtin_amdgcn_mfma_f32_16x16x32_bf16(xh[fm], wh[fn], acc[fm][fn], 0, 0, 0);
        acc[fm][fn] =
            __builtin_amdgcn_mfma_f32_16x16x32_bf16(xl[fm], wh[fn], acc[fm][fn], 0, 0, 0);
      }
  }

  if constexpr (O == 128) {  // gate: zr = sigmoid(acc + bias)
#pragma unroll
    for (int fn = 0; fn < NF; ++fn) {
      int o = colbase + fn * 16 + r16;
      float bb = bias[n * 128 + o];
#pragma unroll
      for (int fm = 0; fm < 4; ++fm) {
#pragma unroll
        for (int r = 0; r < 4; ++r) {
          int b = fm * 16 + q * 4 + r;
          zr_out[((long long)b * kN + n) * 128 + o] = sig_(acc[fm][fn][r] + bb);
        }
      }
    }
  } else {  // update: h = r*s + (1-r)*tanh(acc + bias)
    const float* sptr = (VAR == 1) ? P.s0 : P.s1;
    int o = colbase + r16;
    float bb = bias[n * 64 + o];
#pragma unroll
    for (int fm = 0; fm < 4; ++fm) {
#pragma unroll
      for (int r = 0; r < 4; ++r) {
        int b = fm * 16 + q * 4 + r;
        long long bn = (long long)b * kN + n;
        float rr = P.zr[bn * 128 + 64 + o];
        float ss = sptr[bn * 64 + o];
        float h = rr * ss + (1.f - rr) * tanhf(acc[fm][0][r] + bb);
        state_out[bn * 64 + o] = h;
        if constexpr (VAR == 3) {
          seq_out[(((long long)b * kT + t) * kN + n) * 64 + o] = h;
        }
        if (t == kT - 1) last_out[bn * 64 + o] = h;
      }
    }
  }
}

extern "C" void kernel_launch(void* const* d_in, const int* in_sizes, int n_in, void* d_out,
                              int out_size, void* d_ws, size_t ws_size, hipStream_t stream) {
  (void)in_sizes; (void)n_in; (void)out_size; (void)ws_size;
  const float* x   = (const float*)d_in[0];
  const float* ist = (const float*)d_in[1];
  const float* E   = (const float*)d_in[2];
  const float* gw0 = (const float*)d_in[3];
  const float* gb0 = (const float*)d_in[4];
  const float* uw0 = (const float*)d_in[5];
  const float* ub0 = (const float*)d_in[6];
  const float* gw1 = (const float*)d_in[7];
  const float* gb1 = (const float*)d_in[8];
  const float* uw1 = (const float*)d_in[9];
  const float* ub1 = (const float*)d_in[10];
  float* out = (float*)d_out;

  char* base = (char*)d_ws;
  size_t off = 0;
  auto alloc = [&](size_t bytes) {
    char* p = base + off;
    off += (bytes + 1023) & ~(size_t)1023;
    return p;
  };
  unsigned short* Vth = (unsigned short*)alloc((size_t)8192 * kN * 2);
  unsigned short* Ahh = (unsigned short*)alloc((size_t)kN * kN * 2);
  float* Ax = (float*)alloc((size_t)kB * kT * kN * 2 * 4);
  unsigned short* Wg0h = (unsigned short*)alloc((size_t)kN * 128 * 160 * 2);
  unsigned short* Wu0h = (unsigned short*)alloc((size_t)kN * 64 * 160 * 2);
  unsigned short* Wg1h = (unsigned short*)alloc((size_t)kN * 128 * 256 * 2);
  unsigned short* Wu1h = (unsigned short*)alloc((size_t)kN * 64 * 256 * 2);
  float* Bg0 = (float*)alloc((size_t)kN * 128 * 4);
  float* Bu0 = (float*)alloc((size_t)kN * 64 * 4);
  float* Bg1 = (float*)alloc((size_t)kN * 128 * 4);
  float* Bu1 = (float*)alloc((size_t)kN * 64 * 4);
  float* s0 = (float*)alloc((size_t)BNH * 4);
  float* s1 = (float*)alloc((size_t)BNH * 4);
  float* dx = (float*)alloc((size_t)BNH * 4);
  float* dd = (float*)alloc((size_t)BNH * 2 * 4);  // [d2 | d3]
  float* zr = (float*)alloc((size_t)kB * kN * 128 * 4);
  float* d2 = dd;
  float* d3 = dd + BNH;

  const size_t stateBytes = (size_t)BNH * sizeof(float);
  (void)hipMemcpyAsync(s0, ist, stateBytes, hipMemcpyDeviceToDevice, stream);
  (void)hipMemcpyAsync(s1, ist + BNH, stateBytes, hipMemcpyDeviceToDevice, stream);

  compute_A<<<kN, 256, 0, stream>>>(E, Ahh);
  // x diffusion through the MFMA path: Ax[bt,n,c] = sum_m A[n,m] x[bt,m,c]
  prep_x<<<dim3(16, 24), 256, 0, stream>>>(x, Vth);
  diff_gemm<<<dim3(12, 8), 512, 0, stream>>>(Ahh, Vth, Ax, 1);

  mkw2<<<dim3(128, 8), 256, 0, stream>>>(E, gw0, Wg0h, 128, 132, 160, 66, 1);
  mkw2<<<dim3(64, 8), 256, 0, stream>>>(E, uw0, Wu0h, 64, 132, 160, 66, 1);
  mkw2<<<dim3(128, 8), 256, 0, stream>>>(E, gw1, Wg1h, 128, 256, 256, 128, 0);
  mkw2<<<dim3(64, 8), 256, 0, stream>>>(E, uw1, Wu1h, 64, 256, 256, 128, 0);
  mkb<<<(kN * 128) / 256, 256, 0, stream>>>(E, gb0, Bg0, 128);
  mkb<<<(kN * 64) / 256, 256, 0, stream>>>(E, ub0, Bu0, 64);
  mkb<<<(kN * 128) / 256, 256, 0, stream>>>(E, gb1, Bg1, 128);
  mkb<<<(kN * 64) / 256, 256, 0, stream>>>(E, ub1, Bu1, 64);

  // bootstrap: d2 = A @ s0_init
  prep_split<<<dim3(16, kB, 1), 256, 0, stream>>>(s0, nullptr, nullptr, Vth);
  diff_gemm<<<dim3(32, 8), 512, 0, stream>>>(Ahh, Vth, d2, 6);

  for (int t = 0; t < kT; ++t) {
    // L0 gate (diffused state = d2 from previous step / bootstrap)
    StepPtrs Pg0{s0, s1, zr, x, Ax, d2, d2, d3};
    mfma_node<0, 128, 160><<<kN, 256, 0, stream>>>(Pg0, Wg0h, Bg0, zr, nullptr,
                                                   nullptr, nullptr, t);
    // G1 = A @ (z0*s0) -> dx
    prep_split<<<dim3(16, kB, 1), 256, 0, stream>>>(s0, nullptr, zr, Vth);
    diff_gemm<<<dim3(32, 8), 512, 0, stream>>>(Ahh, Vth, dx, 6);
    // L0 update: s0 <- h0; lasts[0] at t==T-1
    StepPtrs Pu0{s0, s1, zr, x, Ax, dx, d2, d3};
    mfma_node<1, 64, 160><<<kN, 256, 0, stream>>>(Pu0, Wu0h, Bu0, nullptr, s0,
                                                  nullptr, out + OUT0, t);
    // G2 = A @ [h0 ; s1] -> [d2 | d3]
    prep_split<<<dim3(16, kB, 2), 256, 0, stream>>>(s0, s1, nullptr, Vth);
    diff_gemm<<<dim3(64, 8), 512, 0, stream>>>(Ahh, Vth, d2, 6);
    // L1 gate
    StepPtrs P1g{s0, s1, zr, x, Ax, d2, d2, d3};
    mfma_node<2, 128, 256><<<kN, 256, 0, stream>>>(P1g, Wg1h, Bg1, zr, nullptr,
                                                   nullptr, nullptr, t);
    // G3 = A @ (z1*s1) -> dx
    prep_split<<<dim3(16, kB, 1), 256, 0, stream>>>(s1, nullptr, zr, Vth);
    diff_gemm<<<dim3(32, 8), 512, 0, stream>>>(Ahh, Vth, dx, 6);
    // L1 update: s1 <- h1; seq out; lasts[1] at t==T-1
    StepPtrs P1u{s0, s1, zr, x, Ax, d2, d2, dx};
    mfma_node<3, 64, 256><<<kN, 256, 0, stream>>>(P1u, Wu1h, Bu1, nullptr, s1, out,
                                                  out + OUT0 + BNH, t);
  }
}